// Round 6
// baseline (212.854 us; speedup 1.0000x reference)
//
#include <hip/hip_runtime.h>
#include <math.h>

#define F_IN 165
#define HID 16
#define NPB 256         // nodes per bucket
#define NPB_BITS 8
#define MAXB 512        // padded bucket-array size (nbuck=391)
#define CHUNK 6144      // edges per binscatter block
#define SSTAGE 12288    // sortnode LDS staging capacity (avg bucket ~8192)
#define HB_BLOCKS 256   // k_bhist grid

// ---- bucket histogram: LDS-staged, ~100k global atomics total ----
__global__ __launch_bounds__(256) void k_bhist(const int* __restrict__ dst,
                                               int* __restrict__ bhist,
                                               int E, int nbuck) {
    __shared__ int h[MAXB];
    int t = threadIdx.x;
    for (int i = t; i < MAXB; i += 256) h[i] = 0;
    __syncthreads();
    int per = (E + gridDim.x - 1) / gridDim.x;
    int s0 = blockIdx.x * per;
    int s1 = min(E, s0 + per);
    for (int k = s0 + t; k < s1; k += 256)
        atomicAdd(&h[dst[k] >> NPB_BITS], 1);
    __syncthreads();
    for (int i = t; i < nbuck; i += 256) {
        int v = h[i];
        if (v) atomicAdd(&bhist[i], v);
    }
}

// ---- single-block exclusive scan of bucket counts -> bofs, cursor ----
__global__ __launch_bounds__(256) void k_bscan(const int* __restrict__ bhist,
                                               int* __restrict__ bofs,
                                               int* __restrict__ cursor,
                                               int* __restrict__ rowptr,
                                               int nbuck, int N) {
    __shared__ int ps[256];
    int t = threadIdx.x;
    int i0 = 2 * t, i1 = 2 * t + 1;
    int c0 = (i0 < nbuck) ? bhist[i0] : 0;
    int c1 = (i1 < nbuck) ? bhist[i1] : 0;
    int s = c0 + c1;
    ps[t] = s;
    __syncthreads();
    for (int off = 1; off < 256; off <<= 1) {
        int a = (t >= off) ? ps[t - off] : 0;
        __syncthreads();
        ps[t] += a;
        __syncthreads();
    }
    int excl = ps[t] - s;
    if (i0 < nbuck) { bofs[i0] = excl;      cursor[i0] = excl; }
    if (i1 < nbuck) { bofs[i1] = excl + c0; cursor[i1] = excl + c0; }
    if (t == 255) { bofs[nbuck] = ps[255]; rowptr[N] = ps[255]; }
}

// ---- counting-sort edges into bucket-major order, packed (src<<8)|dstlow ----
__global__ __launch_bounds__(256) void k_binscatter(const int* __restrict__ src,
                                                    const int* __restrict__ dst,
                                                    int* __restrict__ cursor,
                                                    unsigned* __restrict__ sedge,
                                                    int E, int nbuck) {
    __shared__ int hist[MAXB];
    __shared__ int lofs[MAXB];
    __shared__ int gbase[MAXB];
    __shared__ int ps[256];
    __shared__ unsigned stage[CHUNK];
    int t = threadIdx.x;
    int e0 = blockIdx.x * CHUNK;
    int n = min(CHUNK, E - e0);

    for (int i = t; i < MAXB; i += 256) hist[i] = 0;
    __syncthreads();
    for (int k = t; k < n; k += 256) atomicAdd(&hist[dst[e0 + k] >> NPB_BITS], 1);
    __syncthreads();

    // block exclusive scan of hist (512 entries, 2 per thread)
    int base = t * 2;
    int h0 = hist[base], h1 = hist[base + 1];
    int s = h0 + h1;
    ps[t] = s;
    __syncthreads();
    for (int off = 1; off < 256; off <<= 1) {
        int a = (t >= off) ? ps[t - off] : 0;
        __syncthreads();
        ps[t] += a;
        __syncthreads();
    }
    int excl = ps[t] - s;
    lofs[base] = excl;
    lofs[base + 1] = excl + h0;
    // reserve global space per non-empty bucket
    for (int i = t; i < nbuck; i += 256) {
        int h = hist[i];
        gbase[i] = h ? atomicAdd(&cursor[i], h) : 0;
    }
    __syncthreads();
    for (int i = t; i < MAXB; i += 256) hist[i] = 0;  // -> local cursor
    __syncthreads();

    // reorder into bucket-major staging
    for (int k = t; k < n; k += 256) {
        int d = dst[e0 + k];
        int sv = src[e0 + k];
        int b = d >> NPB_BITS;
        int r = lofs[b] + atomicAdd(&hist[b], 1);
        stage[r] = ((unsigned)sv << NPB_BITS) | (unsigned)(d & (NPB - 1));
    }
    __syncthreads();

    // coalesced-run write-out; bucket of slot r via binary search in lofs
    for (int r = t; r < n; r += 256) {
        int lo = 0, hi = nbuck - 1;
        while (lo < hi) {
            int mid = (lo + hi + 1) >> 1;
            if (lofs[mid] <= r) lo = mid; else hi = mid - 1;
        }
        sedge[gbase[lo] + (r - lofs[lo])] = stage[r];
    }
}

// ---- within-bucket: node histogram (LDS) -> rowptr + dinv + sorted csr ----
__global__ __launch_bounds__(256) void k_sortnode(const int* __restrict__ bofs,
                                                  const unsigned* __restrict__ sedge,
                                                  int* __restrict__ csr,
                                                  int* __restrict__ rowptr,
                                                  float* __restrict__ dinv, int N) {
    __shared__ int hist[256];
    __shared__ int ps[256];
    __shared__ int lcur[256];
    __shared__ int stage[SSTAGE];
    int b = blockIdx.x, t = threadIdx.x;
    int base = bofs[b];
    int n = bofs[b + 1] - base;
    hist[t] = 0;
    __syncthreads();
    for (int k = t; k < n; k += 256)
        atomicAdd(&hist[sedge[base + k] & (NPB - 1)], 1);
    __syncthreads();
    int c = hist[t];
    ps[t] = c;
    __syncthreads();
    for (int off = 1; off < 256; off <<= 1) {
        int a = (t >= off) ? ps[t - off] : 0;
        __syncthreads();
        ps[t] += a;
        __syncthreads();
    }
    int excl = ps[t] - c;
    int node = b * NPB + t;
    if (node < N) {
        rowptr[node] = base + excl;
        dinv[node] = rsqrtf((float)c + 1.0f);
    }
    lcur[t] = excl;
    __syncthreads();
    bool staged = (n <= SSTAGE);
    for (int k = t; k < n; k += 256) {
        unsigned p = sedge[base + k];
        int d = p & (NPB - 1);
        int pos = atomicAdd(&lcur[d], 1);
        int sv = (int)(p >> NPB_BITS);
        if (staged) stage[pos] = sv;
        else        csr[base + pos] = sv;
    }
    __syncthreads();
    if (staged) {
        for (int k = t; k < n; k += 256) csr[base + k] = stage[k];
    }
}

// ---- g1 = (x @ W1) * dinv[row]   (LDS-tiled, 64 rows/block, unroll-15 ILP) ----
__global__ __launch_bounds__(256) void k_gemm1(const float* __restrict__ x,
                                               const float* __restrict__ W1,
                                               const float* __restrict__ dinv,
                                               float* __restrict__ g1, int N) {
    __shared__ float xs[64 * F_IN];
    int b = blockIdx.x;
    int rows = min(64, N - b * 64);
    int nf = rows * F_IN;
    const float* xbase = x + (long long)b * 64 * F_IN;
    int nf4 = nf >> 2;
    const float4* src4 = (const float4*)xbase;
    float4* xs4 = (float4*)xs;
    for (int i = threadIdx.x; i < nf4; i += 256) xs4[i] = src4[i];
    for (int i = nf4 * 4 + threadIdx.x; i < nf; i += 256) xs[i] = xbase[i];
    __syncthreads();

    int row = threadIdx.x & 63;
    int jq = threadIdx.x >> 6;   // wave-uniform -> W1 via scalar loads
    int gi = b * 64 + row;
    if (gi >= N || row >= rows) return;

    const float* xr = xs + row * F_IN;   // stride 165: coprime w/ 32 banks
    float a0 = 0.f, a1 = 0.f, a2 = 0.f, a3 = 0.f;
    // 165 = 11 * 15: batch 15 independent LDS reads -> one lgkmcnt window
    for (int k0 = 0; k0 < F_IN; k0 += 15) {
        float v[15];
#pragma unroll
        for (int u = 0; u < 15; ++u) v[u] = xr[k0 + u];
#pragma unroll
        for (int u = 0; u < 15; ++u) {
            const float* w = W1 + (k0 + u) * HID + jq * 4;
            a0 = fmaf(v[u], w[0], a0);
            a1 = fmaf(v[u], w[1], a1);
            a2 = fmaf(v[u], w[2], a2);
            a3 = fmaf(v[u], w[3], a3);
        }
    }
    float di = dinv[gi];
    float4 o = make_float4(a0 * di, a1 * di, a2 * di, a3 * di);
    *(float4*)(g1 + (long long)gi * HID + jq * 4) = o;
}

// ---- layer-1 CSR gather, register accumulate, fused bias/relu/W2 -> g2 ----
__global__ __launch_bounds__(256) void k_agg1(const int* __restrict__ rowptr,
                                              const int* __restrict__ csr,
                                              const float* __restrict__ g1,
                                              const float* __restrict__ dinv,
                                              const float* __restrict__ b1,
                                              const float* __restrict__ W2,
                                              float* __restrict__ g2, int N) {
    int gid = blockIdx.x * 256 + threadIdx.x;
    int i = gid >> 4;
    int j = gid & 15;
    if (i >= N) return;
    int e0 = rowptr[i], e1 = rowptr[i + 1];
    float acc = g1[i * HID + j];  // self-loop term
    int e = e0;
    for (; e + 8 <= e1; e += 8) {
        int s0 = csr[e],     s1 = csr[e + 1], s2 = csr[e + 2], s3 = csr[e + 3];
        int s4 = csr[e + 4], s5 = csr[e + 5], s6 = csr[e + 6], s7 = csr[e + 7];
        float v0 = g1[s0 * HID + j], v1 = g1[s1 * HID + j];
        float v2 = g1[s2 * HID + j], v3 = g1[s3 * HID + j];
        float v4 = g1[s4 * HID + j], v5 = g1[s5 * HID + j];
        float v6 = g1[s6 * HID + j], v7 = g1[s7 * HID + j];
        acc += ((v0 + v1) + (v2 + v3)) + ((v4 + v5) + (v6 + v7));
    }
    for (; e < e1; ++e) acc += g1[csr[e] * HID + j];
    float di = dinv[i];
    float v = fmaf(acc, di, b1[j]);
    v = v > 0.f ? v : 0.f;
    float2 w = ((const float2*)W2)[j];
    float c0 = v * w.x;
    float c1 = v * w.y;
    for (int off = 8; off; off >>= 1) {
        c0 += __shfl_xor(c0, off, 16);
        c1 += __shfl_xor(c1, off, 16);
    }
    if (j == 0) ((float2*)g2)[i] = make_float2(c0 * di, c1 * di);
}

// ---- layer-2 CSR gather + fused log_softmax -> out (4 lanes/node) ----
__global__ __launch_bounds__(256) void k_agg2(const int* __restrict__ rowptr,
                                              const int* __restrict__ csr,
                                              const float* __restrict__ g2,
                                              const float* __restrict__ dinv,
                                              const float* __restrict__ b2,
                                              float* __restrict__ out, int N) {
    int gid = blockIdx.x * 256 + threadIdx.x;
    int i = gid >> 2;
    int l = gid & 3;
    if (i >= N) return;
    int e0 = rowptr[i], e1 = rowptr[i + 1];
    float a0 = 0.f, a1 = 0.f;
    int e = e0 + l;
    for (; e + 4 < e1; e += 8) {
        int s0 = csr[e], s1 = csr[e + 4];
        float2 u = ((const float2*)g2)[s0];
        float2 w = ((const float2*)g2)[s1];
        a0 += u.x + w.x;
        a1 += u.y + w.y;
    }
    for (; e < e1; e += 4) {
        int s = csr[e];
        float2 u = ((const float2*)g2)[s];
        a0 += u.x;
        a1 += u.y;
    }
    a0 += __shfl_xor(a0, 1, 4); a0 += __shfl_xor(a0, 2, 4);
    a1 += __shfl_xor(a1, 1, 4); a1 += __shfl_xor(a1, 2, 4);
    if (l == 0) {
        float2 self = ((const float2*)g2)[i];
        float di = dinv[i];
        float A = fmaf(a0 + self.x, di, b2[0]);
        float B = fmaf(a1 + self.y, di, b2[1]);
        float m = fmaxf(A, B);
        float lse = m + logf(expf(A - m) + expf(B - m));
        ((float2*)out)[i] = make_float2(A - lse, B - lse);
    }
}

extern "C" void kernel_launch(void* const* d_in, const int* in_sizes, int n_in,
                              void* d_out, int out_size, void* d_ws, size_t ws_size,
                              hipStream_t stream) {
    const float* x  = (const float*)d_in[0];
    const int*   ei = (const int*)d_in[1];
    const float* W1 = (const float*)d_in[2];
    const float* b1 = (const float*)d_in[3];
    const float* W2 = (const float*)d_in[4];
    const float* b2 = (const float*)d_in[5];
    float* out = (float*)d_out;

    int N = in_sizes[0] / F_IN;
    int E = in_sizes[1] / 2;
    const int* src = ei;
    const int* dst = ei + E;
    int nbuck = (N + NPB - 1) >> NPB_BITS;

    int* bhist    = (int*)d_ws;                     // MAXB
    int* bofs     = bhist + MAXB;                   // MAXB+1
    int* cursor   = bofs + MAXB + 1;                // MAXB
    int* rowptr   = cursor + MAXB;                  // N+1
    unsigned* sedge = (unsigned*)(rowptr + N + 1);  // E
    int* csr      = (int*)(sedge + E);              // E
    float* dinv   = (float*)(csr + E);              // N
    float* g1     = dinv + N;                       // 16N
    float* g2     = g1 + (long long)16 * N;         // 2N

    hipMemsetAsync(bhist, 0, (size_t)MAXB * sizeof(int), stream);

    k_bhist<<<HB_BLOCKS, 256, 0, stream>>>(dst, bhist, E, nbuck);
    k_bscan<<<1, 256, 0, stream>>>(bhist, bofs, cursor, rowptr, nbuck, N);
    k_binscatter<<<(E + CHUNK - 1) / CHUNK, 256, 0, stream>>>(src, dst, cursor, sedge, E, nbuck);
    k_sortnode<<<nbuck, 256, 0, stream>>>(bofs, sedge, csr, rowptr, dinv, N);

    k_gemm1<<<(N + 63) / 64, 256, 0, stream>>>(x, W1, dinv, g1, N);

    k_agg1<<<(N * 16 + 255) / 256, 256, 0, stream>>>(rowptr, csr, g1, dinv, b1, W2, g2, N);
    k_agg2<<<(N * 4 + 255) / 256, 256, 0, stream>>>(rowptr, csr, g2, dinv, b2, out, N);
}

// Round 7
// 193.440 us; speedup vs baseline: 1.1004x; 1.1004x over previous
//
#include <hip/hip_runtime.h>
#include <math.h>

#define F_IN 165
#define HID 16
#define NPB 256         // nodes per bucket
#define NPB_BITS 8
#define MAXB 512        // padded bucket-array size (nbuck=391)
#define CHUNK 6144      // edges per binscatter block
#define SSTAGE 12288    // sortnode LDS staging capacity (avg bucket ~8192)
#define HB_BLOCKS 256   // k_bhist grid

// ---- bucket histogram: LDS-staged, ~100k global atomics total ----
__global__ __launch_bounds__(256) void k_bhist(const int* __restrict__ dst,
                                               int* __restrict__ bhist,
                                               int E, int nbuck) {
    __shared__ int h[MAXB];
    int t = threadIdx.x;
    for (int i = t; i < MAXB; i += 256) h[i] = 0;
    __syncthreads();
    int per = (E + gridDim.x - 1) / gridDim.x;
    int s0 = blockIdx.x * per;
    int s1 = min(E, s0 + per);
    for (int k = s0 + t; k < s1; k += 256)
        atomicAdd(&h[dst[k] >> NPB_BITS], 1);
    __syncthreads();
    for (int i = t; i < nbuck; i += 256) {
        int v = h[i];
        if (v) atomicAdd(&bhist[i], v);
    }
}

// ---- single-block exclusive scan of bucket counts -> bofs, cursor ----
__global__ __launch_bounds__(256) void k_bscan(const int* __restrict__ bhist,
                                               int* __restrict__ bofs,
                                               int* __restrict__ cursor,
                                               int* __restrict__ rowptr,
                                               int nbuck, int N) {
    __shared__ int ps[256];
    int t = threadIdx.x;
    int i0 = 2 * t, i1 = 2 * t + 1;
    int c0 = (i0 < nbuck) ? bhist[i0] : 0;
    int c1 = (i1 < nbuck) ? bhist[i1] : 0;
    int s = c0 + c1;
    ps[t] = s;
    __syncthreads();
    for (int off = 1; off < 256; off <<= 1) {
        int a = (t >= off) ? ps[t - off] : 0;
        __syncthreads();
        ps[t] += a;
        __syncthreads();
    }
    int excl = ps[t] - s;
    if (i0 < nbuck) { bofs[i0] = excl;      cursor[i0] = excl; }
    if (i1 < nbuck) { bofs[i1] = excl + c0; cursor[i1] = excl + c0; }
    if (t == 255) { bofs[nbuck] = ps[255]; rowptr[N] = ps[255]; }
}

// ---- counting-sort edges into bucket-major order, packed (src<<8)|dstlow ----
__global__ __launch_bounds__(256) void k_binscatter(const int* __restrict__ src,
                                                    const int* __restrict__ dst,
                                                    int* __restrict__ cursor,
                                                    unsigned* __restrict__ sedge,
                                                    int E, int nbuck) {
    __shared__ int hist[MAXB];
    __shared__ int lofs[MAXB];
    __shared__ int gbase[MAXB];
    __shared__ int ps[256];
    __shared__ unsigned stage[CHUNK];
    int t = threadIdx.x;
    int e0 = blockIdx.x * CHUNK;
    int n = min(CHUNK, E - e0);

    for (int i = t; i < MAXB; i += 256) hist[i] = 0;
    __syncthreads();
    for (int k = t; k < n; k += 256) atomicAdd(&hist[dst[e0 + k] >> NPB_BITS], 1);
    __syncthreads();

    // block exclusive scan of hist (512 entries, 2 per thread)
    int base = t * 2;
    int h0 = hist[base], h1 = hist[base + 1];
    int s = h0 + h1;
    ps[t] = s;
    __syncthreads();
    for (int off = 1; off < 256; off <<= 1) {
        int a = (t >= off) ? ps[t - off] : 0;
        __syncthreads();
        ps[t] += a;
        __syncthreads();
    }
    int excl = ps[t] - s;
    lofs[base] = excl;
    lofs[base + 1] = excl + h0;
    // reserve global space per non-empty bucket
    for (int i = t; i < nbuck; i += 256) {
        int h = hist[i];
        gbase[i] = h ? atomicAdd(&cursor[i], h) : 0;
    }
    __syncthreads();
    for (int i = t; i < MAXB; i += 256) hist[i] = 0;  // -> local cursor
    __syncthreads();

    // reorder into bucket-major staging
    for (int k = t; k < n; k += 256) {
        int d = dst[e0 + k];
        int sv = src[e0 + k];
        int b = d >> NPB_BITS;
        int r = lofs[b] + atomicAdd(&hist[b], 1);
        stage[r] = ((unsigned)sv << NPB_BITS) | (unsigned)(d & (NPB - 1));
    }
    __syncthreads();

    // coalesced-run write-out; bucket of slot r via binary search in lofs
    for (int r = t; r < n; r += 256) {
        int lo = 0, hi = nbuck - 1;
        while (lo < hi) {
            int mid = (lo + hi + 1) >> 1;
            if (lofs[mid] <= r) lo = mid; else hi = mid - 1;
        }
        sedge[gbase[lo] + (r - lofs[lo])] = stage[r];
    }
}

// ---- within-bucket: node histogram (LDS) -> rowptr + dinv + sorted csr ----
__global__ __launch_bounds__(256) void k_sortnode(const int* __restrict__ bofs,
                                                  const unsigned* __restrict__ sedge,
                                                  int* __restrict__ csr,
                                                  int* __restrict__ rowptr,
                                                  float* __restrict__ dinv, int N) {
    __shared__ int hist[256];
    __shared__ int ps[256];
    __shared__ int lcur[256];
    __shared__ int stage[SSTAGE];
    int b = blockIdx.x, t = threadIdx.x;
    int base = bofs[b];
    int n = bofs[b + 1] - base;
    hist[t] = 0;
    __syncthreads();
    for (int k = t; k < n; k += 256)
        atomicAdd(&hist[sedge[base + k] & (NPB - 1)], 1);
    __syncthreads();
    int c = hist[t];
    ps[t] = c;
    __syncthreads();
    for (int off = 1; off < 256; off <<= 1) {
        int a = (t >= off) ? ps[t - off] : 0;
        __syncthreads();
        ps[t] += a;
        __syncthreads();
    }
    int excl = ps[t] - c;
    int node = b * NPB + t;
    if (node < N) {
        rowptr[node] = base + excl;
        dinv[node] = rsqrtf((float)c + 1.0f);
    }
    lcur[t] = excl;
    __syncthreads();
    bool staged = (n <= SSTAGE);
    for (int k = t; k < n; k += 256) {
        unsigned p = sedge[base + k];
        int d = p & (NPB - 1);
        int pos = atomicAdd(&lcur[d], 1);
        int sv = (int)(p >> NPB_BITS);
        if (staged) stage[pos] = sv;
        else        csr[base + pos] = sv;
    }
    __syncthreads();
    if (staged) {
        for (int k = t; k < n; k += 256) csr[base + k] = stage[k];
    }
}

// ---- g1 = (x @ W1) * dinv[row] ----
// No x staging: each thread reads its own row direct from global (float4 +
// alignment peel, 41 independent loads in flight). W1 broadcast from LDS.
// 2 threads per row (8 cols each), 128 rows per 256-thread block.
#define FMA4(vv, kk)                                                   \
    {                                                                  \
        const float4* wk = (const float4*)(ws + (kk) * HID + half8);   \
        float4 wa = wk[0], wb = wk[1];                                 \
        aA.x = fmaf((vv), wa.x, aA.x); aA.y = fmaf((vv), wa.y, aA.y);  \
        aA.z = fmaf((vv), wa.z, aA.z); aA.w = fmaf((vv), wa.w, aA.w);  \
        aB.x = fmaf((vv), wb.x, aB.x); aB.y = fmaf((vv), wb.y, aB.y);  \
        aB.z = fmaf((vv), wb.z, aB.z); aB.w = fmaf((vv), wb.w, aB.w);  \
    }

__global__ __launch_bounds__(256) void k_gemm1(const float* __restrict__ x,
                                               const float* __restrict__ W1,
                                               const float* __restrict__ dinv,
                                               float* __restrict__ g1, int N) {
    __shared__ float ws[F_IN * HID];   // 10.5 KB: no occupancy cap
    int t = threadIdx.x;
    {
        const float4* w4 = (const float4*)W1;
        float4* s4 = (float4*)ws;
#pragma unroll
        for (int u = 0; u < 3; ++u) {
            int i = t + u * 256;
            if (i < (F_IN * HID) / 4) s4[i] = w4[i];
        }
    }
    __syncthreads();
    int row = blockIdx.x * 128 + (t & 127);
    int half8 = (t >> 7) * 8;
    if (row >= N) return;
    const float* xr = x + (long long)row * F_IN;
    float4 aA = make_float4(0.f, 0.f, 0.f, 0.f);
    float4 aB = make_float4(0.f, 0.f, 0.f, 0.f);

    int p = (4 - (row & 3)) & 3;   // dwords to 16B boundary (row*165 % 4 == row % 4)
    for (int k = 0; k < p; ++k) { float v = xr[k]; FMA4(v, k); }

    const float4* xr4 = (const float4*)(xr + p);
    int n4 = (F_IN - p) >> 2;      // 40 or 41
    int q = 0;
    for (; q + 4 <= n4; q += 4) {
        float4 v0 = xr4[q], v1 = xr4[q + 1], v2 = xr4[q + 2], v3 = xr4[q + 3];
        int kb = p + q * 4;
        FMA4(v0.x, kb + 0)  FMA4(v0.y, kb + 1)  FMA4(v0.z, kb + 2)  FMA4(v0.w, kb + 3)
        FMA4(v1.x, kb + 4)  FMA4(v1.y, kb + 5)  FMA4(v1.z, kb + 6)  FMA4(v1.w, kb + 7)
        FMA4(v2.x, kb + 8)  FMA4(v2.y, kb + 9)  FMA4(v2.z, kb + 10) FMA4(v2.w, kb + 11)
        FMA4(v3.x, kb + 12) FMA4(v3.y, kb + 13) FMA4(v3.z, kb + 14) FMA4(v3.w, kb + 15)
    }
    for (; q < n4; ++q) {
        float4 v = xr4[q];
        int kb = p + q * 4;
        FMA4(v.x, kb) FMA4(v.y, kb + 1) FMA4(v.z, kb + 2) FMA4(v.w, kb + 3)
    }
    for (int k = p + n4 * 4; k < F_IN; ++k) { float v = xr[k]; FMA4(v, k); }

    float di = dinv[row];
    float* o = g1 + (long long)row * HID + half8;
    *(float4*)(o)     = make_float4(aA.x * di, aA.y * di, aA.z * di, aA.w * di);
    *(float4*)(o + 4) = make_float4(aB.x * di, aB.y * di, aB.z * di, aB.w * di);
}

// ---- layer-1 CSR gather, register accumulate, fused bias/relu/W2 -> g2 ----
__global__ __launch_bounds__(256) void k_agg1(const int* __restrict__ rowptr,
                                              const int* __restrict__ csr,
                                              const float* __restrict__ g1,
                                              const float* __restrict__ dinv,
                                              const float* __restrict__ b1,
                                              const float* __restrict__ W2,
                                              float* __restrict__ g2, int N) {
    int gid = blockIdx.x * 256 + threadIdx.x;
    int i = gid >> 4;
    int j = gid & 15;
    if (i >= N) return;
    int e0 = rowptr[i], e1 = rowptr[i + 1];
    float acc = g1[i * HID + j];  // self-loop term
    int e = e0;
    for (; e + 8 <= e1; e += 8) {
        int s0 = csr[e],     s1 = csr[e + 1], s2 = csr[e + 2], s3 = csr[e + 3];
        int s4 = csr[e + 4], s5 = csr[e + 5], s6 = csr[e + 6], s7 = csr[e + 7];
        float v0 = g1[s0 * HID + j], v1 = g1[s1 * HID + j];
        float v2 = g1[s2 * HID + j], v3 = g1[s3 * HID + j];
        float v4 = g1[s4 * HID + j], v5 = g1[s5 * HID + j];
        float v6 = g1[s6 * HID + j], v7 = g1[s7 * HID + j];
        acc += ((v0 + v1) + (v2 + v3)) + ((v4 + v5) + (v6 + v7));
    }
    for (; e < e1; ++e) acc += g1[csr[e] * HID + j];
    float di = dinv[i];
    float v = fmaf(acc, di, b1[j]);
    v = v > 0.f ? v : 0.f;
    float2 w = ((const float2*)W2)[j];
    float c0 = v * w.x;
    float c1 = v * w.y;
    for (int off = 8; off; off >>= 1) {
        c0 += __shfl_xor(c0, off, 16);
        c1 += __shfl_xor(c1, off, 16);
    }
    if (j == 0) ((float2*)g2)[i] = make_float2(c0 * di, c1 * di);
}

// ---- layer-2 CSR gather + fused log_softmax -> out (4 lanes/node) ----
__global__ __launch_bounds__(256) void k_agg2(const int* __restrict__ rowptr,
                                              const int* __restrict__ csr,
                                              const float* __restrict__ g2,
                                              const float* __restrict__ dinv,
                                              const float* __restrict__ b2,
                                              float* __restrict__ out, int N) {
    int gid = blockIdx.x * 256 + threadIdx.x;
    int i = gid >> 2;
    int l = gid & 3;
    if (i >= N) return;
    int e0 = rowptr[i], e1 = rowptr[i + 1];
    float a0 = 0.f, a1 = 0.f;
    int e = e0 + l;
    for (; e + 4 < e1; e += 8) {
        int s0 = csr[e], s1 = csr[e + 4];
        float2 u = ((const float2*)g2)[s0];
        float2 w = ((const float2*)g2)[s1];
        a0 += u.x + w.x;
        a1 += u.y + w.y;
    }
    for (; e < e1; e += 4) {
        int s = csr[e];
        float2 u = ((const float2*)g2)[s];
        a0 += u.x;
        a1 += u.y;
    }
    a0 += __shfl_xor(a0, 1, 4); a0 += __shfl_xor(a0, 2, 4);
    a1 += __shfl_xor(a1, 1, 4); a1 += __shfl_xor(a1, 2, 4);
    if (l == 0) {
        float2 self = ((const float2*)g2)[i];
        float di = dinv[i];
        float A = fmaf(a0 + self.x, di, b2[0]);
        float B = fmaf(a1 + self.y, di, b2[1]);
        float m = fmaxf(A, B);
        float lse = m + logf(expf(A - m) + expf(B - m));
        ((float2*)out)[i] = make_float2(A - lse, B - lse);
    }
}

extern "C" void kernel_launch(void* const* d_in, const int* in_sizes, int n_in,
                              void* d_out, int out_size, void* d_ws, size_t ws_size,
                              hipStream_t stream) {
    const float* x  = (const float*)d_in[0];
    const int*   ei = (const int*)d_in[1];
    const float* W1 = (const float*)d_in[2];
    const float* b1 = (const float*)d_in[3];
    const float* W2 = (const float*)d_in[4];
    const float* b2 = (const float*)d_in[5];
    float* out = (float*)d_out;

    int N = in_sizes[0] / F_IN;
    int E = in_sizes[1] / 2;
    const int* src = ei;
    const int* dst = ei + E;
    int nbuck = (N + NPB - 1) >> NPB_BITS;

    int* bhist    = (int*)d_ws;                     // MAXB
    int* bofs     = bhist + MAXB;                   // MAXB+1
    int* cursor   = bofs + MAXB + 1;                // MAXB
    int* rowptr   = cursor + MAXB;                  // N+1
    unsigned* sedge = (unsigned*)(rowptr + N + 1);  // E
    int* csr      = (int*)(sedge + E);              // E
    float* dinv   = (float*)(csr + E);              // N
    float* g1     = dinv + N;                       // 16N
    float* g2     = g1 + (long long)16 * N;         // 2N

    hipMemsetAsync(bhist, 0, (size_t)MAXB * sizeof(int), stream);

    k_bhist<<<HB_BLOCKS, 256, 0, stream>>>(dst, bhist, E, nbuck);
    k_bscan<<<1, 256, 0, stream>>>(bhist, bofs, cursor, rowptr, nbuck, N);
    k_binscatter<<<(E + CHUNK - 1) / CHUNK, 256, 0, stream>>>(src, dst, cursor, sedge, E, nbuck);
    k_sortnode<<<nbuck, 256, 0, stream>>>(bofs, sedge, csr, rowptr, dinv, N);

    k_gemm1<<<(N + 127) / 128, 256, 0, stream>>>(x, W1, dinv, g1, N);

    k_agg1<<<(N * 16 + 255) / 256, 256, 0, stream>>>(rowptr, csr, g1, dinv, b1, W2, g2, N);
    k_agg2<<<(N * 4 + 255) / 256, 256, 0, stream>>>(rowptr, csr, g2, dinv, b2, out, N);
}

// Round 8
// 186.400 us; speedup vs baseline: 1.1419x; 1.0378x over previous
//
#include <hip/hip_runtime.h>
#include <math.h>

#define F_IN 165
#define HID 16
#define NPB 256         // nodes per bucket
#define NPB_BITS 8
#define MAXB 512        // padded bucket-array size (nbuck=391)
#define CHUNK 4096      // edges per binscatter block
#define SSTAGE 12288    // sortnode LDS staging capacity (avg bucket ~8192)
#define HB_BLOCKS 256   // k_bhist grid

// ---- bucket histogram: LDS-staged, ~100k global atomics total ----
__global__ __launch_bounds__(256) void k_bhist(const int* __restrict__ dst,
                                               int* __restrict__ bhist,
                                               int E, int nbuck) {
    __shared__ int h[MAXB];
    int t = threadIdx.x;
    for (int i = t; i < MAXB; i += 256) h[i] = 0;
    __syncthreads();
    int per = (E + gridDim.x - 1) / gridDim.x;
    int s0 = blockIdx.x * per;
    int s1 = min(E, s0 + per);
    for (int k = s0 + t; k < s1; k += 256)
        atomicAdd(&h[dst[k] >> NPB_BITS], 1);
    __syncthreads();
    for (int i = t; i < nbuck; i += 256) {
        int v = h[i];
        if (v) atomicAdd(&bhist[i], v);
    }
}

// ---- single-block exclusive scan of bucket counts -> bofs, cursor ----
__global__ __launch_bounds__(256) void k_bscan(const int* __restrict__ bhist,
                                               int* __restrict__ bofs,
                                               int* __restrict__ cursor,
                                               int* __restrict__ rowptr,
                                               int nbuck, int N) {
    __shared__ int ps[256];
    int t = threadIdx.x;
    int i0 = 2 * t, i1 = 2 * t + 1;
    int c0 = (i0 < nbuck) ? bhist[i0] : 0;
    int c1 = (i1 < nbuck) ? bhist[i1] : 0;
    int s = c0 + c1;
    ps[t] = s;
    __syncthreads();
    for (int off = 1; off < 256; off <<= 1) {
        int a = (t >= off) ? ps[t - off] : 0;
        __syncthreads();
        ps[t] += a;
        __syncthreads();
    }
    int excl = ps[t] - s;
    if (i0 < nbuck) { bofs[i0] = excl;      cursor[i0] = excl; }
    if (i1 < nbuck) { bofs[i1] = excl + c0; cursor[i1] = excl + c0; }
    if (t == 255) { bofs[nbuck] = ps[255]; rowptr[N] = ps[255]; }
}

// ---- counting-sort edges into bucket-major order, packed (src<<8)|dstlow ----
// Write-out address precomputed during reorder: no binary search.
__global__ __launch_bounds__(256) void k_binscatter(const int* __restrict__ src,
                                                    const int* __restrict__ dst,
                                                    int* __restrict__ cursor,
                                                    unsigned* __restrict__ sedge,
                                                    int E, int nbuck) {
    __shared__ int hist[MAXB];
    __shared__ int lofs[MAXB];
    __shared__ int dlt[MAXB];       // gbase[b] - lofs[b]
    __shared__ int ps[256];
    __shared__ unsigned stage[CHUNK];
    __shared__ int gaddr[CHUNK];
    int t = threadIdx.x;
    int e0 = blockIdx.x * CHUNK;
    int n = min(CHUNK, E - e0);

    for (int i = t; i < MAXB; i += 256) hist[i] = 0;
    __syncthreads();
    for (int k = t; k < n; k += 256) atomicAdd(&hist[dst[e0 + k] >> NPB_BITS], 1);
    __syncthreads();

    // block exclusive scan of hist (512 entries, 2 per thread)
    int base = t * 2;
    int h0 = hist[base], h1 = hist[base + 1];
    int s = h0 + h1;
    ps[t] = s;
    __syncthreads();
    for (int off = 1; off < 256; off <<= 1) {
        int a = (t >= off) ? ps[t - off] : 0;
        __syncthreads();
        ps[t] += a;
        __syncthreads();
    }
    int excl = ps[t] - s;
    lofs[base] = excl;
    lofs[base + 1] = excl + h0;
    __syncthreads();
    // reserve global space per non-empty bucket; dlt = gbase - lofs
    for (int i = t; i < nbuck; i += 256) {
        int h = hist[i];
        dlt[i] = (h ? atomicAdd(&cursor[i], h) : 0) - lofs[i];
    }
    __syncthreads();
    for (int i = t; i < MAXB; i += 256) hist[i] = 0;  // -> local cursor
    __syncthreads();

    // reorder into bucket-major staging; final address computed here
    for (int k = t; k < n; k += 256) {
        int d = dst[e0 + k];
        int sv = src[e0 + k];
        int b = d >> NPB_BITS;
        int r = lofs[b] + atomicAdd(&hist[b], 1);
        stage[r] = ((unsigned)sv << NPB_BITS) | (unsigned)(d & (NPB - 1));
        gaddr[r] = dlt[b] + r;
    }
    __syncthreads();

    // write-out: two independent stride-1 LDS reads + store (depth-1 chain)
    for (int r = t; r < n; r += 256)
        sedge[gaddr[r]] = stage[r];
}

// ---- within-bucket: node histogram (LDS) -> rowptr + dinv + sorted csr ----
__global__ __launch_bounds__(256) void k_sortnode(const int* __restrict__ bofs,
                                                  const unsigned* __restrict__ sedge,
                                                  int* __restrict__ csr,
                                                  int* __restrict__ rowptr,
                                                  float* __restrict__ dinv, int N) {
    __shared__ int hist[256];
    __shared__ int ps[256];
    __shared__ int lcur[256];
    __shared__ int stage[SSTAGE];
    int b = blockIdx.x, t = threadIdx.x;
    int base = bofs[b];
    int n = bofs[b + 1] - base;
    hist[t] = 0;
    __syncthreads();
    for (int k = t; k < n; k += 256)
        atomicAdd(&hist[sedge[base + k] & (NPB - 1)], 1);
    __syncthreads();
    int c = hist[t];
    ps[t] = c;
    __syncthreads();
    for (int off = 1; off < 256; off <<= 1) {
        int a = (t >= off) ? ps[t - off] : 0;
        __syncthreads();
        ps[t] += a;
        __syncthreads();
    }
    int excl = ps[t] - c;
    int node = b * NPB + t;
    if (node < N) {
        rowptr[node] = base + excl;
        dinv[node] = rsqrtf((float)c + 1.0f);
    }
    lcur[t] = excl;
    __syncthreads();
    bool staged = (n <= SSTAGE);
    for (int k = t; k < n; k += 256) {
        unsigned p = sedge[base + k];
        int d = p & (NPB - 1);
        int pos = atomicAdd(&lcur[d], 1);
        int sv = (int)(p >> NPB_BITS);
        if (staged) stage[pos] = sv;
        else        csr[base + pos] = sv;
    }
    __syncthreads();
    if (staged) {
        for (int k = t; k < n; k += 256) csr[base + k] = stage[k];
    }
}

// ---- g1 = (x @ W1) * dinv[row] ----
// No x staging: each thread reads its own row direct from global (float4 +
// alignment peel, 41 independent loads in flight). W1 broadcast from LDS.
// 2 threads per row (8 cols each), 128 rows per 256-thread block.
#define FMA4(vv, kk)                                                   \
    {                                                                  \
        const float4* wk = (const float4*)(ws + (kk) * HID + half8);   \
        float4 wa = wk[0], wb = wk[1];                                 \
        aA.x = fmaf((vv), wa.x, aA.x); aA.y = fmaf((vv), wa.y, aA.y);  \
        aA.z = fmaf((vv), wa.z, aA.z); aA.w = fmaf((vv), wa.w, aA.w);  \
        aB.x = fmaf((vv), wb.x, aB.x); aB.y = fmaf((vv), wb.y, aB.y);  \
        aB.z = fmaf((vv), wb.z, aB.z); aB.w = fmaf((vv), wb.w, aB.w);  \
    }

__global__ __launch_bounds__(256) void k_gemm1(const float* __restrict__ x,
                                               const float* __restrict__ W1,
                                               const float* __restrict__ dinv,
                                               float* __restrict__ g1, int N) {
    __shared__ float ws[F_IN * HID];   // 10.5 KB: no occupancy cap
    int t = threadIdx.x;
    {
        const float4* w4 = (const float4*)W1;
        float4* s4 = (float4*)ws;
#pragma unroll
        for (int u = 0; u < 3; ++u) {
            int i = t + u * 256;
            if (i < (F_IN * HID) / 4) s4[i] = w4[i];
        }
    }
    __syncthreads();
    int row = blockIdx.x * 128 + (t & 127);
    int half8 = (t >> 7) * 8;
    if (row >= N) return;
    const float* xr = x + (long long)row * F_IN;
    float4 aA = make_float4(0.f, 0.f, 0.f, 0.f);
    float4 aB = make_float4(0.f, 0.f, 0.f, 0.f);

    int p = (4 - (row & 3)) & 3;   // dwords to 16B boundary (row*165 % 4 == row % 4)
    for (int k = 0; k < p; ++k) { float v = xr[k]; FMA4(v, k); }

    const float4* xr4 = (const float4*)(xr + p);
    int n4 = (F_IN - p) >> 2;      // 40 or 41
    int q = 0;
    for (; q + 4 <= n4; q += 4) {
        float4 v0 = xr4[q], v1 = xr4[q + 1], v2 = xr4[q + 2], v3 = xr4[q + 3];
        int kb = p + q * 4;
        FMA4(v0.x, kb + 0)  FMA4(v0.y, kb + 1)  FMA4(v0.z, kb + 2)  FMA4(v0.w, kb + 3)
        FMA4(v1.x, kb + 4)  FMA4(v1.y, kb + 5)  FMA4(v1.z, kb + 6)  FMA4(v1.w, kb + 7)
        FMA4(v2.x, kb + 8)  FMA4(v2.y, kb + 9)  FMA4(v2.z, kb + 10) FMA4(v2.w, kb + 11)
        FMA4(v3.x, kb + 12) FMA4(v3.y, kb + 13) FMA4(v3.z, kb + 14) FMA4(v3.w, kb + 15)
    }
    for (; q < n4; ++q) {
        float4 v = xr4[q];
        int kb = p + q * 4;
        FMA4(v.x, kb) FMA4(v.y, kb + 1) FMA4(v.z, kb + 2) FMA4(v.w, kb + 3)
    }
    for (int k = p + n4 * 4; k < F_IN; ++k) { float v = xr[k]; FMA4(v, k); }

    float di = dinv[row];
    float* o = g1 + (long long)row * HID + half8;
    *(float4*)(o)     = make_float4(aA.x * di, aA.y * di, aA.z * di, aA.w * di);
    *(float4*)(o + 4) = make_float4(aB.x * di, aB.y * di, aB.z * di, aB.w * di);
}

// ---- layer-1 CSR gather, register accumulate, fused bias/relu/W2 -> g2 ----
__global__ __launch_bounds__(256) void k_agg1(const int* __restrict__ rowptr,
                                              const int* __restrict__ csr,
                                              const float* __restrict__ g1,
                                              const float* __restrict__ dinv,
                                              const float* __restrict__ b1,
                                              const float* __restrict__ W2,
                                              float* __restrict__ g2, int N) {
    int gid = blockIdx.x * 256 + threadIdx.x;
    int i = gid >> 4;
    int j = gid & 15;
    if (i >= N) return;
    int e0 = rowptr[i], e1 = rowptr[i + 1];
    float acc = g1[i * HID + j];  // self-loop term
    int e = e0;
    for (; e + 8 <= e1; e += 8) {
        int s0 = csr[e],     s1 = csr[e + 1], s2 = csr[e + 2], s3 = csr[e + 3];
        int s4 = csr[e + 4], s5 = csr[e + 5], s6 = csr[e + 6], s7 = csr[e + 7];
        float v0 = g1[s0 * HID + j], v1 = g1[s1 * HID + j];
        float v2 = g1[s2 * HID + j], v3 = g1[s3 * HID + j];
        float v4 = g1[s4 * HID + j], v5 = g1[s5 * HID + j];
        float v6 = g1[s6 * HID + j], v7 = g1[s7 * HID + j];
        acc += ((v0 + v1) + (v2 + v3)) + ((v4 + v5) + (v6 + v7));
    }
    for (; e < e1; ++e) acc += g1[csr[e] * HID + j];
    float di = dinv[i];
    float v = fmaf(acc, di, b1[j]);
    v = v > 0.f ? v : 0.f;
    float2 w = ((const float2*)W2)[j];
    float c0 = v * w.x;
    float c1 = v * w.y;
    for (int off = 8; off; off >>= 1) {
        c0 += __shfl_xor(c0, off, 16);
        c1 += __shfl_xor(c1, off, 16);
    }
    if (j == 0) ((float2*)g2)[i] = make_float2(c0 * di, c1 * di);
}

// ---- layer-2 CSR gather + fused log_softmax -> out (4 lanes/node) ----
__global__ __launch_bounds__(256) void k_agg2(const int* __restrict__ rowptr,
                                              const int* __restrict__ csr,
                                              const float* __restrict__ g2,
                                              const float* __restrict__ dinv,
                                              const float* __restrict__ b2,
                                              float* __restrict__ out, int N) {
    int gid = blockIdx.x * 256 + threadIdx.x;
    int i = gid >> 2;
    int l = gid & 3;
    if (i >= N) return;
    int e0 = rowptr[i], e1 = rowptr[i + 1];
    float a0 = 0.f, a1 = 0.f;
    int e = e0 + l;
    for (; e + 4 < e1; e += 8) {
        int s0 = csr[e], s1 = csr[e + 4];
        float2 u = ((const float2*)g2)[s0];
        float2 w = ((const float2*)g2)[s1];
        a0 += u.x + w.x;
        a1 += u.y + w.y;
    }
    for (; e < e1; e += 4) {
        int s = csr[e];
        float2 u = ((const float2*)g2)[s];
        a0 += u.x;
        a1 += u.y;
    }
    a0 += __shfl_xor(a0, 1, 4); a0 += __shfl_xor(a0, 2, 4);
    a1 += __shfl_xor(a1, 1, 4); a1 += __shfl_xor(a1, 2, 4);
    if (l == 0) {
        float2 self = ((const float2*)g2)[i];
        float di = dinv[i];
        float A = fmaf(a0 + self.x, di, b2[0]);
        float B = fmaf(a1 + self.y, di, b2[1]);
        float m = fmaxf(A, B);
        float lse = m + logf(expf(A - m) + expf(B - m));
        ((float2*)out)[i] = make_float2(A - lse, B - lse);
    }
}

extern "C" void kernel_launch(void* const* d_in, const int* in_sizes, int n_in,
                              void* d_out, int out_size, void* d_ws, size_t ws_size,
                              hipStream_t stream) {
    const float* x  = (const float*)d_in[0];
    const int*   ei = (const int*)d_in[1];
    const float* W1 = (const float*)d_in[2];
    const float* b1 = (const float*)d_in[3];
    const float* W2 = (const float*)d_in[4];
    const float* b2 = (const float*)d_in[5];
    float* out = (float*)d_out;

    int N = in_sizes[0] / F_IN;
    int E = in_sizes[1] / 2;
    const int* src = ei;
    const int* dst = ei + E;
    int nbuck = (N + NPB - 1) >> NPB_BITS;

    int* bhist    = (int*)d_ws;                     // MAXB
    int* bofs     = bhist + MAXB;                   // MAXB+1
    int* cursor   = bofs + MAXB + 1;                // MAXB
    int* rowptr   = cursor + MAXB;                  // N+1
    unsigned* sedge = (unsigned*)(rowptr + N + 1);  // E
    int* csr      = (int*)(sedge + E);              // E
    float* dinv   = (float*)(csr + E);              // N
    float* g1     = dinv + N;                       // 16N
    float* g2     = g1 + (long long)16 * N;         // 2N

    hipMemsetAsync(bhist, 0, (size_t)MAXB * sizeof(int), stream);

    k_bhist<<<HB_BLOCKS, 256, 0, stream>>>(dst, bhist, E, nbuck);
    k_bscan<<<1, 256, 0, stream>>>(bhist, bofs, cursor, rowptr, nbuck, N);
    k_binscatter<<<(E + CHUNK - 1) / CHUNK, 256, 0, stream>>>(src, dst, cursor, sedge, E, nbuck);
    k_sortnode<<<nbuck, 256, 0, stream>>>(bofs, sedge, csr, rowptr, dinv, N);

    k_gemm1<<<(N + 127) / 128, 256, 0, stream>>>(x, W1, dinv, g1, N);

    k_agg1<<<(N * 16 + 255) / 256, 256, 0, stream>>>(rowptr, csr, g1, dinv, b1, W2, g2, N);
    k_agg2<<<(N * 4 + 255) / 256, 256, 0, stream>>>(rowptr, csr, g2, dinv, b2, out, N);
}

// Round 9
// 164.821 us; speedup vs baseline: 1.2914x; 1.1309x over previous
//
#include <hip/hip_runtime.h>
#include <math.h>

#define F_IN 165
#define HID 16
#define NPB 256         // nodes per bucket
#define NPB_BITS 8
#define MAXB 512        // padded bucket-array size (nbuck=391)
#define CHUNK 4096      // edges per binscatter block
#define EPT 16          // CHUNK/256
#define SSTAGE 12288    // sortnode LDS staging capacity (avg bucket ~8192)
#define HB_BLOCKS 256   // k_bhist grid

__device__ __forceinline__ unsigned pk_bf16(float lo, float hi) {
    unsigned a = __float_as_uint(lo), b = __float_as_uint(hi);
    a += 0x7FFF + ((a >> 16) & 1);       // RNE
    b += 0x7FFF + ((b >> 16) & 1);
    return (a >> 16) | (b & 0xFFFF0000u);
}
#define BF_LO(w) __uint_as_float((w) << 16)
#define BF_HI(w) __uint_as_float((w) & 0xFFFF0000u)

// ---- bucket histogram: LDS-staged, ~100k global atomics total ----
__global__ __launch_bounds__(256) void k_bhist(const int* __restrict__ dst,
                                               int* __restrict__ bhist,
                                               int E, int nbuck) {
    __shared__ int h[MAXB];
    int t = threadIdx.x;
    for (int i = t; i < MAXB; i += 256) h[i] = 0;
    __syncthreads();
    int per = (E + gridDim.x - 1) / gridDim.x;
    int s0 = blockIdx.x * per;
    int s1 = min(E, s0 + per);
    for (int k = s0 + t; k < s1; k += 256)
        atomicAdd(&h[dst[k] >> NPB_BITS], 1);
    __syncthreads();
    for (int i = t; i < nbuck; i += 256) {
        int v = h[i];
        if (v) atomicAdd(&bhist[i], v);
    }
}

// ---- single-block exclusive scan of bucket counts -> bofs, cursor ----
__global__ __launch_bounds__(256) void k_bscan(const int* __restrict__ bhist,
                                               int* __restrict__ bofs,
                                               int* __restrict__ cursor,
                                               int* __restrict__ rowptr,
                                               int nbuck, int N) {
    __shared__ int ps[256];
    int t = threadIdx.x;
    int i0 = 2 * t, i1 = 2 * t + 1;
    int c0 = (i0 < nbuck) ? bhist[i0] : 0;
    int c1 = (i1 < nbuck) ? bhist[i1] : 0;
    int s = c0 + c1;
    ps[t] = s;
    __syncthreads();
    for (int off = 1; off < 256; off <<= 1) {
        int a = (t >= off) ? ps[t - off] : 0;
        __syncthreads();
        ps[t] += a;
        __syncthreads();
    }
    int excl = ps[t] - s;
    if (i0 < nbuck) { bofs[i0] = excl;      cursor[i0] = excl; }
    if (i1 < nbuck) { bofs[i1] = excl + c0; cursor[i1] = excl + c0; }
    if (t == 255) { bofs[nbuck] = ps[255]; rowptr[N] = ps[255]; }
}

// ---- counting-sort edges into bucket-major order, packed (src<<8)|dstlow ----
// Edges register-cached; stage+addr fused in one uint2 (single ds_write_b64).
__global__ __launch_bounds__(256) void k_binscatter(const int* __restrict__ src,
                                                    const int* __restrict__ dst,
                                                    int* __restrict__ cursor,
                                                    unsigned* __restrict__ sedge,
                                                    int E, int nbuck) {
    __shared__ int hist[MAXB];
    __shared__ int lofs[MAXB];
    __shared__ int dlt[MAXB];       // gbase[b] - lofs[b]
    __shared__ int ps[256];
    __shared__ uint2 stg[CHUNK];
    int t = threadIdx.x;
    int e0 = blockIdx.x * CHUNK;
    int n = min(CHUNK, E - e0);

    int d[EPT], sv[EPT];
#pragma unroll
    for (int u = 0; u < EPT; ++u) {
        int k = t + u * 256;
        d[u]  = (k < n) ? dst[e0 + k] : -1;
        sv[u] = (k < n) ? src[e0 + k] : 0;
    }
    for (int i = t; i < MAXB; i += 256) hist[i] = 0;
    __syncthreads();
#pragma unroll
    for (int u = 0; u < EPT; ++u)
        if (d[u] >= 0) atomicAdd(&hist[d[u] >> NPB_BITS], 1);
    __syncthreads();

    // block exclusive scan of hist (512 entries, 2 per thread)
    int base = t * 2;
    int h0 = hist[base], h1 = hist[base + 1];
    int s = h0 + h1;
    ps[t] = s;
    __syncthreads();
    for (int off = 1; off < 256; off <<= 1) {
        int a = (t >= off) ? ps[t - off] : 0;
        __syncthreads();
        ps[t] += a;
        __syncthreads();
    }
    int excl = ps[t] - s;
    lofs[base] = excl;
    lofs[base + 1] = excl + h0;
    __syncthreads();
    // reserve global space per non-empty bucket; dlt = gbase - lofs
    for (int i = t; i < nbuck; i += 256) {
        int h = hist[i];
        dlt[i] = (h ? atomicAdd(&cursor[i], h) : 0) - lofs[i];
    }
    __syncthreads();
    for (int i = t; i < MAXB; i += 256) hist[i] = 0;  // -> local cursor
    __syncthreads();

    // reorder into bucket-major staging; final address fused in .y
#pragma unroll
    for (int u = 0; u < EPT; ++u) {
        if (d[u] < 0) continue;
        int b = d[u] >> NPB_BITS;
        int r = lofs[b] + atomicAdd(&hist[b], 1);
        stg[r] = make_uint2(((unsigned)sv[u] << NPB_BITS) | (unsigned)(d[u] & (NPB - 1)),
                            (unsigned)(dlt[b] + r));
    }
    __syncthreads();

    // write-out: stride-1 LDS read pair + store (depth-1 chain)
    for (int r = t; r < n; r += 256) {
        uint2 v = stg[r];
        sedge[v.y] = v.x;
    }
}

// ---- within-bucket: node histogram (LDS) -> rowptr + dinv + sorted csr ----
__global__ __launch_bounds__(256) void k_sortnode(const int* __restrict__ bofs,
                                                  const unsigned* __restrict__ sedge,
                                                  int* __restrict__ csr,
                                                  int* __restrict__ rowptr,
                                                  float* __restrict__ dinv, int N) {
    __shared__ int hist[256];
    __shared__ int ps[256];
    __shared__ int lcur[256];
    __shared__ int stage[SSTAGE];
    int b = blockIdx.x, t = threadIdx.x;
    int base = bofs[b];
    int n = bofs[b + 1] - base;
    hist[t] = 0;
    __syncthreads();
    for (int k = t; k < n; k += 256)
        atomicAdd(&hist[sedge[base + k] & (NPB - 1)], 1);
    __syncthreads();
    int c = hist[t];
    ps[t] = c;
    __syncthreads();
    for (int off = 1; off < 256; off <<= 1) {
        int a = (t >= off) ? ps[t - off] : 0;
        __syncthreads();
        ps[t] += a;
        __syncthreads();
    }
    int excl = ps[t] - c;
    int node = b * NPB + t;
    if (node < N) {
        rowptr[node] = base + excl;
        dinv[node] = rsqrtf((float)c + 1.0f);
    }
    lcur[t] = excl;
    __syncthreads();
    bool staged = (n <= SSTAGE);
    for (int k = t; k < n; k += 256) {
        unsigned p = sedge[base + k];
        int d = p & (NPB - 1);
        int pos = atomicAdd(&lcur[d], 1);
        int sv = (int)(p >> NPB_BITS);
        if (staged) stage[pos] = sv;
        else        csr[base + pos] = sv;
    }
    __syncthreads();
    if (staged) {
        for (int k = t; k < n; k += 256) csr[base + k] = stage[k];
    }
}

// ---- g1 = bf16((x @ W1) * dinv[row]) : 32B row, halves gather traffic ----
#define FMA4(vv, kk)                                                   \
    {                                                                  \
        const float4* wk = (const float4*)(ws + (kk) * HID + half8);   \
        float4 wa = wk[0], wb = wk[1];                                 \
        aA.x = fmaf((vv), wa.x, aA.x); aA.y = fmaf((vv), wa.y, aA.y);  \
        aA.z = fmaf((vv), wa.z, aA.z); aA.w = fmaf((vv), wa.w, aA.w);  \
        aB.x = fmaf((vv), wb.x, aB.x); aB.y = fmaf((vv), wb.y, aB.y);  \
        aB.z = fmaf((vv), wb.z, aB.z); aB.w = fmaf((vv), wb.w, aB.w);  \
    }

__global__ __launch_bounds__(256) void k_gemm1(const float* __restrict__ x,
                                               const float* __restrict__ W1,
                                               const float* __restrict__ dinv,
                                               unsigned* __restrict__ g1, int N) {
    __shared__ float ws[F_IN * HID];   // 10.5 KB: no occupancy cap
    int t = threadIdx.x;
    {
        const float4* w4 = (const float4*)W1;
        float4* s4 = (float4*)ws;
#pragma unroll
        for (int u = 0; u < 3; ++u) {
            int i = t + u * 256;
            if (i < (F_IN * HID) / 4) s4[i] = w4[i];
        }
    }
    __syncthreads();
    int row = blockIdx.x * 128 + (t & 127);
    int half8 = (t >> 7) * 8;
    if (row >= N) return;
    const float* xr = x + (long long)row * F_IN;
    float4 aA = make_float4(0.f, 0.f, 0.f, 0.f);
    float4 aB = make_float4(0.f, 0.f, 0.f, 0.f);

    int p = (4 - (row & 3)) & 3;   // dwords to 16B boundary
    for (int k = 0; k < p; ++k) { float v = xr[k]; FMA4(v, k); }

    const float4* xr4 = (const float4*)(xr + p);
    int n4 = (F_IN - p) >> 2;      // 40 or 41
    int q = 0;
    for (; q + 4 <= n4; q += 4) {
        float4 v0 = xr4[q], v1 = xr4[q + 1], v2 = xr4[q + 2], v3 = xr4[q + 3];
        int kb = p + q * 4;
        FMA4(v0.x, kb + 0)  FMA4(v0.y, kb + 1)  FMA4(v0.z, kb + 2)  FMA4(v0.w, kb + 3)
        FMA4(v1.x, kb + 4)  FMA4(v1.y, kb + 5)  FMA4(v1.z, kb + 6)  FMA4(v1.w, kb + 7)
        FMA4(v2.x, kb + 8)  FMA4(v2.y, kb + 9)  FMA4(v2.z, kb + 10) FMA4(v2.w, kb + 11)
        FMA4(v3.x, kb + 12) FMA4(v3.y, kb + 13) FMA4(v3.z, kb + 14) FMA4(v3.w, kb + 15)
    }
    for (; q < n4; ++q) {
        float4 v = xr4[q];
        int kb = p + q * 4;
        FMA4(v.x, kb) FMA4(v.y, kb + 1) FMA4(v.z, kb + 2) FMA4(v.w, kb + 3)
    }
    for (int k = p + n4 * 4; k < F_IN; ++k) { float v = xr[k]; FMA4(v, k); }

    float di = dinv[row];
    uint4 o = make_uint4(pk_bf16(aA.x * di, aA.y * di), pk_bf16(aA.z * di, aA.w * di),
                         pk_bf16(aB.x * di, aB.y * di), pk_bf16(aB.z * di, aB.w * di));
    *(uint4*)(g1 + (long long)row * 8 + (half8 >> 1)) = o;
}

// ---- layer-1 CSR gather (bf16 rows), fp32 accum, fused bias/relu/W2 -> g2 ----
// 8 lanes per node; each lane owns 2 features via one packed uint.
__global__ __launch_bounds__(256) void k_agg1(const int* __restrict__ rowptr,
                                              const int* __restrict__ csr,
                                              const unsigned* __restrict__ g1,
                                              const float* __restrict__ dinv,
                                              const float* __restrict__ b1,
                                              const float* __restrict__ W2,
                                              float* __restrict__ g2, int N) {
    int gid = blockIdx.x * 256 + threadIdx.x;
    int i = gid >> 3;
    int j = gid & 7;
    if (i >= N) return;
    int e0 = rowptr[i], e1 = rowptr[i + 1];
    unsigned w0 = g1[i * 8 + j];           // self-loop term
    float a0 = BF_LO(w0), a1 = BF_HI(w0);
    int e = e0;
    for (; e + 8 <= e1; e += 8) {
        int s0 = csr[e],     s1 = csr[e + 1], s2 = csr[e + 2], s3 = csr[e + 3];
        int s4 = csr[e + 4], s5 = csr[e + 5], s6 = csr[e + 6], s7 = csr[e + 7];
        unsigned u0 = g1[s0 * 8 + j], u1 = g1[s1 * 8 + j];
        unsigned u2 = g1[s2 * 8 + j], u3 = g1[s3 * 8 + j];
        unsigned u4 = g1[s4 * 8 + j], u5 = g1[s5 * 8 + j];
        unsigned u6 = g1[s6 * 8 + j], u7 = g1[s7 * 8 + j];
        a0 += ((BF_LO(u0) + BF_LO(u1)) + (BF_LO(u2) + BF_LO(u3))) +
              ((BF_LO(u4) + BF_LO(u5)) + (BF_LO(u6) + BF_LO(u7)));
        a1 += ((BF_HI(u0) + BF_HI(u1)) + (BF_HI(u2) + BF_HI(u3))) +
              ((BF_HI(u4) + BF_HI(u5)) + (BF_HI(u6) + BF_HI(u7)));
    }
    for (; e < e1; ++e) {
        unsigned u = g1[csr[e] * 8 + j];
        a0 += BF_LO(u);
        a1 += BF_HI(u);
    }
    float di = dinv[i];
    float v0 = fmaf(a0, di, b1[2 * j]);     v0 = v0 > 0.f ? v0 : 0.f;
    float v1 = fmaf(a1, di, b1[2 * j + 1]); v1 = v1 > 0.f ? v1 : 0.f;
    float4 w = ((const float4*)W2)[j];      // W2[2j][0..1], W2[2j+1][0..1]
    float c0 = fmaf(v1, w.z, v0 * w.x);
    float c1 = fmaf(v1, w.w, v0 * w.y);
    for (int off = 4; off; off >>= 1) {
        c0 += __shfl_xor(c0, off, 8);
        c1 += __shfl_xor(c1, off, 8);
    }
    if (j == 0) ((float2*)g2)[i] = make_float2(c0 * di, c1 * di);
}

// ---- layer-2 CSR gather + fused log_softmax -> out (4 lanes/node) ----
__global__ __launch_bounds__(256) void k_agg2(const int* __restrict__ rowptr,
                                              const int* __restrict__ csr,
                                              const float* __restrict__ g2,
                                              const float* __restrict__ dinv,
                                              const float* __restrict__ b2,
                                              float* __restrict__ out, int N) {
    int gid = blockIdx.x * 256 + threadIdx.x;
    int i = gid >> 2;
    int l = gid & 3;
    if (i >= N) return;
    int e0 = rowptr[i], e1 = rowptr[i + 1];
    float a0 = 0.f, a1 = 0.f;
    int e = e0 + l;
    for (; e + 4 < e1; e += 8) {
        int s0 = csr[e], s1 = csr[e + 4];
        float2 u = ((const float2*)g2)[s0];
        float2 w = ((const float2*)g2)[s1];
        a0 += u.x + w.x;
        a1 += u.y + w.y;
    }
    for (; e < e1; e += 4) {
        int s = csr[e];
        float2 u = ((const float2*)g2)[s];
        a0 += u.x;
        a1 += u.y;
    }
    a0 += __shfl_xor(a0, 1, 4); a0 += __shfl_xor(a0, 2, 4);
    a1 += __shfl_xor(a1, 1, 4); a1 += __shfl_xor(a1, 2, 4);
    if (l == 0) {
        float2 self = ((const float2*)g2)[i];
        float di = dinv[i];
        float A = fmaf(a0 + self.x, di, b2[0]);
        float B = fmaf(a1 + self.y, di, b2[1]);
        float m = fmaxf(A, B);
        float lse = m + logf(expf(A - m) + expf(B - m));
        ((float2*)out)[i] = make_float2(A - lse, B - lse);
    }
}

extern "C" void kernel_launch(void* const* d_in, const int* in_sizes, int n_in,
                              void* d_out, int out_size, void* d_ws, size_t ws_size,
                              hipStream_t stream) {
    const float* x  = (const float*)d_in[0];
    const int*   ei = (const int*)d_in[1];
    const float* W1 = (const float*)d_in[2];
    const float* b1 = (const float*)d_in[3];
    const float* W2 = (const float*)d_in[4];
    const float* b2 = (const float*)d_in[5];
    float* out = (float*)d_out;

    int N = in_sizes[0] / F_IN;
    int E = in_sizes[1] / 2;
    const int* src = ei;
    const int* dst = ei + E;
    int nbuck = (N + NPB - 1) >> NPB_BITS;

    int* bhist    = (int*)d_ws;                     // MAXB
    int* bofs     = bhist + MAXB;                   // MAXB+1
    int* cursor   = bofs + MAXB + 1;                // MAXB
    int* rowptr   = cursor + MAXB;                  // N+1
    unsigned* sedge = (unsigned*)(rowptr + N + 1);  // E
    int* csr      = (int*)(sedge + E);              // E
    float* dinv   = (float*)(csr + E);              // N
    unsigned* g1  = (unsigned*)(dinv + N);          // 8N (bf16 rows)
    float* g2     = (float*)(g1 + (long long)8 * N);// 2N

    hipMemsetAsync(bhist, 0, (size_t)MAXB * sizeof(int), stream);

    k_bhist<<<HB_BLOCKS, 256, 0, stream>>>(dst, bhist, E, nbuck);
    k_bscan<<<1, 256, 0, stream>>>(bhist, bofs, cursor, rowptr, nbuck, N);
    k_binscatter<<<(E + CHUNK - 1) / CHUNK, 256, 0, stream>>>(src, dst, cursor, sedge, E, nbuck);
    k_sortnode<<<nbuck, 256, 0, stream>>>(bofs, sedge, csr, rowptr, dinv, N);

    k_gemm1<<<(N + 127) / 128, 256, 0, stream>>>(x, W1, dinv, g1, N);

    k_agg1<<<(N * 8 + 255) / 256, 256, 0, stream>>>(rowptr, csr, g1, dinv, b1, W2, g2, N);
    k_agg2<<<(N * 4 + 255) / 256, 256, 0, stream>>>(rowptr, csr, g2, dinv, b2, out, N);
}

// Round 10
// 158.526 us; speedup vs baseline: 1.3427x; 1.0397x over previous
//
#include <hip/hip_runtime.h>
#include <math.h>

#define F_IN 165
#define HID 16
#define NPB 256         // nodes per bucket
#define NPB_BITS 8
#define MAXB 512        // padded bucket-array size (nbuck=391)
#define CHUNK 4096      // edges per binscatter block
#define EPT 16          // CHUNK/256
#define SSTAGE 12288    // sortnode LDS staging capacity (avg bucket ~8192)
#define HB_BLOCKS 256   // k_bhist grid

__device__ __forceinline__ unsigned pk_bf16(float lo, float hi) {
    unsigned a = __float_as_uint(lo), b = __float_as_uint(hi);
    a += 0x7FFF + ((a >> 16) & 1);       // RNE
    b += 0x7FFF + ((b >> 16) & 1);
    return (a >> 16) | (b & 0xFFFF0000u);
}
#define BF_LO(w) __uint_as_float((w) << 16)
#define BF_HI(w) __uint_as_float((w) & 0xFFFF0000u)

// ---- bucket histogram: LDS-staged, ~100k global atomics total ----
__global__ __launch_bounds__(256) void k_bhist(const int* __restrict__ dst,
                                               int* __restrict__ bhist,
                                               int E, int nbuck) {
    __shared__ int h[MAXB];
    int t = threadIdx.x;
    for (int i = t; i < MAXB; i += 256) h[i] = 0;
    __syncthreads();
    int per = (E + gridDim.x - 1) / gridDim.x;
    int s0 = blockIdx.x * per;
    int s1 = min(E, s0 + per);
    for (int k = s0 + t; k < s1; k += 256)
        atomicAdd(&h[dst[k] >> NPB_BITS], 1);
    __syncthreads();
    for (int i = t; i < nbuck; i += 256) {
        int v = h[i];
        if (v) atomicAdd(&bhist[i], v);
    }
}

// ---- single-block exclusive scan of bucket counts -> bofs, cursor ----
__global__ __launch_bounds__(256) void k_bscan(const int* __restrict__ bhist,
                                               int* __restrict__ bofs,
                                               int* __restrict__ cursor,
                                               int* __restrict__ rowptr,
                                               int nbuck, int N) {
    __shared__ int ps[256];
    int t = threadIdx.x;
    int i0 = 2 * t, i1 = 2 * t + 1;
    int c0 = (i0 < nbuck) ? bhist[i0] : 0;
    int c1 = (i1 < nbuck) ? bhist[i1] : 0;
    int s = c0 + c1;
    ps[t] = s;
    __syncthreads();
    for (int off = 1; off < 256; off <<= 1) {
        int a = (t >= off) ? ps[t - off] : 0;
        __syncthreads();
        ps[t] += a;
        __syncthreads();
    }
    int excl = ps[t] - s;
    if (i0 < nbuck) { bofs[i0] = excl;      cursor[i0] = excl; }
    if (i1 < nbuck) { bofs[i1] = excl + c0; cursor[i1] = excl + c0; }
    if (t == 255) { bofs[nbuck] = ps[255]; rowptr[N] = ps[255]; }
}

// ---- counting-sort edges into bucket-major order, packed (src<<8)|dstlow ----
// Edges register-cached; stage+addr fused in one uint2 (single ds_write_b64).
__global__ __launch_bounds__(256) void k_binscatter(const int* __restrict__ src,
                                                    const int* __restrict__ dst,
                                                    int* __restrict__ cursor,
                                                    unsigned* __restrict__ sedge,
                                                    int E, int nbuck) {
    __shared__ int hist[MAXB];
    __shared__ int lofs[MAXB];
    __shared__ int dlt[MAXB];       // gbase[b] - lofs[b]
    __shared__ int ps[256];
    __shared__ uint2 stg[CHUNK];
    int t = threadIdx.x;
    int e0 = blockIdx.x * CHUNK;
    int n = min(CHUNK, E - e0);

    int d[EPT], sv[EPT];
#pragma unroll
    for (int u = 0; u < EPT; ++u) {
        int k = t + u * 256;
        d[u]  = (k < n) ? dst[e0 + k] : -1;
        sv[u] = (k < n) ? src[e0 + k] : 0;
    }
    for (int i = t; i < MAXB; i += 256) hist[i] = 0;
    __syncthreads();
#pragma unroll
    for (int u = 0; u < EPT; ++u)
        if (d[u] >= 0) atomicAdd(&hist[d[u] >> NPB_BITS], 1);
    __syncthreads();

    // block exclusive scan of hist (512 entries, 2 per thread)
    int base = t * 2;
    int h0 = hist[base], h1 = hist[base + 1];
    int s = h0 + h1;
    ps[t] = s;
    __syncthreads();
    for (int off = 1; off < 256; off <<= 1) {
        int a = (t >= off) ? ps[t - off] : 0;
        __syncthreads();
        ps[t] += a;
        __syncthreads();
    }
    int excl = ps[t] - s;
    lofs[base] = excl;
    lofs[base + 1] = excl + h0;
    __syncthreads();
    // reserve global space per non-empty bucket; dlt = gbase - lofs
    for (int i = t; i < nbuck; i += 256) {
        int h = hist[i];
        dlt[i] = (h ? atomicAdd(&cursor[i], h) : 0) - lofs[i];
    }
    __syncthreads();
    for (int i = t; i < MAXB; i += 256) hist[i] = 0;  // -> local cursor
    __syncthreads();

    // reorder into bucket-major staging; final address fused in .y
#pragma unroll
    for (int u = 0; u < EPT; ++u) {
        if (d[u] < 0) continue;
        int b = d[u] >> NPB_BITS;
        int r = lofs[b] + atomicAdd(&hist[b], 1);
        stg[r] = make_uint2(((unsigned)sv[u] << NPB_BITS) | (unsigned)(d[u] & (NPB - 1)),
                            (unsigned)(dlt[b] + r));
    }
    __syncthreads();

    // write-out: stride-1 LDS read pair + store (depth-1 chain)
    for (int r = t; r < n; r += 256) {
        uint2 v = stg[r];
        sedge[v.y] = v.x;
    }
}

// ---- within-bucket: node histogram (LDS) -> rowptr + dinv + sorted csr ----
__global__ __launch_bounds__(256) void k_sortnode(const int* __restrict__ bofs,
                                                  const unsigned* __restrict__ sedge,
                                                  int* __restrict__ csr,
                                                  int* __restrict__ rowptr,
                                                  float* __restrict__ dinv, int N) {
    __shared__ int hist[256];
    __shared__ int ps[256];
    __shared__ int lcur[256];
    __shared__ int stage[SSTAGE];
    int b = blockIdx.x, t = threadIdx.x;
    int base = bofs[b];
    int n = bofs[b + 1] - base;
    hist[t] = 0;
    __syncthreads();
    for (int k = t; k < n; k += 256)
        atomicAdd(&hist[sedge[base + k] & (NPB - 1)], 1);
    __syncthreads();
    int c = hist[t];
    ps[t] = c;
    __syncthreads();
    for (int off = 1; off < 256; off <<= 1) {
        int a = (t >= off) ? ps[t - off] : 0;
        __syncthreads();
        ps[t] += a;
        __syncthreads();
    }
    int excl = ps[t] - c;
    int node = b * NPB + t;
    if (node < N) {
        rowptr[node] = base + excl;
        dinv[node] = rsqrtf((float)c + 1.0f);
    }
    lcur[t] = excl;
    __syncthreads();
    bool staged = (n <= SSTAGE);
    for (int k = t; k < n; k += 256) {
        unsigned p = sedge[base + k];
        int d = p & (NPB - 1);
        int pos = atomicAdd(&lcur[d], 1);
        int sv = (int)(p >> NPB_BITS);
        if (staged) stage[pos] = sv;
        else        csr[base + pos] = sv;
    }
    __syncthreads();
    if (staged) {
        for (int k = t; k < n; k += 256) csr[base + k] = stage[k];
    }
}

// ---- g1 = bf16((x @ W1) * dinv[row]) ----
// 4 threads per row (4 cols each over all k): 400k threads = 24 waves/CU.
// Sibling lanes issue identical x addresses -> coalescer merges; W1 from LDS
// with 4 unique addrs/wave-instr (broadcast). No reduction needed.
#define FMA1(vv, kk)                                                   \
    {                                                                  \
        float4 w = *(const float4*)(ws + (kk) * HID + c4);             \
        acc.x = fmaf((vv), w.x, acc.x); acc.y = fmaf((vv), w.y, acc.y);\
        acc.z = fmaf((vv), w.z, acc.z); acc.w = fmaf((vv), w.w, acc.w);\
    }

__global__ __launch_bounds__(256) void k_gemm1(const float* __restrict__ x,
                                               const float* __restrict__ W1,
                                               const float* __restrict__ dinv,
                                               unsigned* __restrict__ g1, int N) {
    __shared__ float ws[F_IN * HID];   // 10.5 KB
    int t = threadIdx.x;
    {
        const float4* w4 = (const float4*)W1;
        float4* s4 = (float4*)ws;
#pragma unroll
        for (int u = 0; u < 3; ++u) {
            int i = t + u * 256;
            if (i < (F_IN * HID) / 4) s4[i] = w4[i];
        }
    }
    __syncthreads();
    int gid = blockIdx.x * 256 + t;
    int row = gid >> 2;
    int c4 = (gid & 3) << 2;
    if (row >= N) return;
    const float* xr = x + (long long)row * F_IN;
    float4 acc = make_float4(0.f, 0.f, 0.f, 0.f);

    int p = (4 - (row & 3)) & 3;   // dwords to 16B boundary
    for (int k = 0; k < p; ++k) { float v = xr[k]; FMA1(v, k); }

    const float4* xr4 = (const float4*)(xr + p);
    int n4 = (F_IN - p) >> 2;      // 40 or 41
    int q = 0;
    for (; q + 4 <= n4; q += 4) {
        float4 v0 = xr4[q], v1 = xr4[q + 1], v2 = xr4[q + 2], v3 = xr4[q + 3];
        int kb = p + q * 4;
        FMA1(v0.x, kb + 0)  FMA1(v0.y, kb + 1)  FMA1(v0.z, kb + 2)  FMA1(v0.w, kb + 3)
        FMA1(v1.x, kb + 4)  FMA1(v1.y, kb + 5)  FMA1(v1.z, kb + 6)  FMA1(v1.w, kb + 7)
        FMA1(v2.x, kb + 8)  FMA1(v2.y, kb + 9)  FMA1(v2.z, kb + 10) FMA1(v2.w, kb + 11)
        FMA1(v3.x, kb + 12) FMA1(v3.y, kb + 13) FMA1(v3.z, kb + 14) FMA1(v3.w, kb + 15)
    }
    for (; q < n4; ++q) {
        float4 v = xr4[q];
        int kb = p + q * 4;
        FMA1(v.x, kb) FMA1(v.y, kb + 1) FMA1(v.z, kb + 2) FMA1(v.w, kb + 3)
    }
    for (int k = p + n4 * 4; k < F_IN; ++k) { float v = xr[k]; FMA1(v, k); }

    float di = dinv[row];
    uint2 o = make_uint2(pk_bf16(acc.x * di, acc.y * di),
                         pk_bf16(acc.z * di, acc.w * di));
    *(uint2*)(g1 + (long long)row * 8 + (gid & 3) * 2) = o;
}

// ---- layer-1 CSR gather (bf16 rows), fp32 accum, fused bias/relu/W2 -> g2 ----
// 8 lanes per node; each lane owns 2 features via one packed uint.
__global__ __launch_bounds__(256) void k_agg1(const int* __restrict__ rowptr,
                                              const int* __restrict__ csr,
                                              const unsigned* __restrict__ g1,
                                              const float* __restrict__ dinv,
                                              const float* __restrict__ b1,
                                              const float* __restrict__ W2,
                                              float* __restrict__ g2, int N) {
    int gid = blockIdx.x * 256 + threadIdx.x;
    int i = gid >> 3;
    int j = gid & 7;
    if (i >= N) return;
    int e0 = rowptr[i], e1 = rowptr[i + 1];
    unsigned w0 = g1[i * 8 + j];           // self-loop term
    float a0 = BF_LO(w0), a1 = BF_HI(w0);
    int e = e0;
    for (; e + 8 <= e1; e += 8) {
        int s0 = csr[e],     s1 = csr[e + 1], s2 = csr[e + 2], s3 = csr[e + 3];
        int s4 = csr[e + 4], s5 = csr[e + 5], s6 = csr[e + 6], s7 = csr[e + 7];
        unsigned u0 = g1[s0 * 8 + j], u1 = g1[s1 * 8 + j];
        unsigned u2 = g1[s2 * 8 + j], u3 = g1[s3 * 8 + j];
        unsigned u4 = g1[s4 * 8 + j], u5 = g1[s5 * 8 + j];
        unsigned u6 = g1[s6 * 8 + j], u7 = g1[s7 * 8 + j];
        a0 += ((BF_LO(u0) + BF_LO(u1)) + (BF_LO(u2) + BF_LO(u3))) +
              ((BF_LO(u4) + BF_LO(u5)) + (BF_LO(u6) + BF_LO(u7)));
        a1 += ((BF_HI(u0) + BF_HI(u1)) + (BF_HI(u2) + BF_HI(u3))) +
              ((BF_HI(u4) + BF_HI(u5)) + (BF_HI(u6) + BF_HI(u7)));
    }
    for (; e < e1; ++e) {
        unsigned u = g1[csr[e] * 8 + j];
        a0 += BF_LO(u);
        a1 += BF_HI(u);
    }
    float di = dinv[i];
    float v0 = fmaf(a0, di, b1[2 * j]);     v0 = v0 > 0.f ? v0 : 0.f;
    float v1 = fmaf(a1, di, b1[2 * j + 1]); v1 = v1 > 0.f ? v1 : 0.f;
    float4 w = ((const float4*)W2)[j];      // W2[2j][0..1], W2[2j+1][0..1]
    float c0 = fmaf(v1, w.z, v0 * w.x);
    float c1 = fmaf(v1, w.w, v0 * w.y);
    for (int off = 4; off; off >>= 1) {
        c0 += __shfl_xor(c0, off, 8);
        c1 += __shfl_xor(c1, off, 8);
    }
    if (j == 0) ((float2*)g2)[i] = make_float2(c0 * di, c1 * di);
}

// ---- layer-2 CSR gather + fused log_softmax -> out (4 lanes/node) ----
__global__ __launch_bounds__(256) void k_agg2(const int* __restrict__ rowptr,
                                              const int* __restrict__ csr,
                                              const float* __restrict__ g2,
                                              const float* __restrict__ dinv,
                                              const float* __restrict__ b2,
                                              float* __restrict__ out, int N) {
    int gid = blockIdx.x * 256 + threadIdx.x;
    int i = gid >> 2;
    int l = gid & 3;
    if (i >= N) return;
    int e0 = rowptr[i], e1 = rowptr[i + 1];
    float a0 = 0.f, a1 = 0.f;
    int e = e0 + l;
    for (; e + 4 < e1; e += 8) {
        int s0 = csr[e], s1 = csr[e + 4];
        float2 u = ((const float2*)g2)[s0];
        float2 w = ((const float2*)g2)[s1];
        a0 += u.x + w.x;
        a1 += u.y + w.y;
    }
    for (; e < e1; e += 4) {
        int s = csr[e];
        float2 u = ((const float2*)g2)[s];
        a0 += u.x;
        a1 += u.y;
    }
    a0 += __shfl_xor(a0, 1, 4); a0 += __shfl_xor(a0, 2, 4);
    a1 += __shfl_xor(a1, 1, 4); a1 += __shfl_xor(a1, 2, 4);
    if (l == 0) {
        float2 self = ((const float2*)g2)[i];
        float di = dinv[i];
        float A = fmaf(a0 + self.x, di, b2[0]);
        float B = fmaf(a1 + self.y, di, b2[1]);
        float m = fmaxf(A, B);
        float lse = m + logf(expf(A - m) + expf(B - m));
        ((float2*)out)[i] = make_float2(A - lse, B - lse);
    }
}

extern "C" void kernel_launch(void* const* d_in, const int* in_sizes, int n_in,
                              void* d_out, int out_size, void* d_ws, size_t ws_size,
                              hipStream_t stream) {
    const float* x  = (const float*)d_in[0];
    const int*   ei = (const int*)d_in[1];
    const float* W1 = (const float*)d_in[2];
    const float* b1 = (const float*)d_in[3];
    const float* W2 = (const float*)d_in[4];
    const float* b2 = (const float*)d_in[5];
    float* out = (float*)d_out;

    int N = in_sizes[0] / F_IN;
    int E = in_sizes[1] / 2;
    const int* src = ei;
    const int* dst = ei + E;
    int nbuck = (N + NPB - 1) >> NPB_BITS;

    int* bhist    = (int*)d_ws;                     // MAXB
    int* bofs     = bhist + MAXB;                   // MAXB+1
    int* cursor   = bofs + MAXB + 1;                // MAXB
    int* rowptr   = cursor + MAXB;                  // N+1
    unsigned* sedge = (unsigned*)(rowptr + N + 1);  // E
    int* csr      = (int*)(sedge + E);              // E
    float* dinv   = (float*)(csr + E);              // N
    unsigned* g1  = (unsigned*)(dinv + N);          // 8N (bf16 rows)
    float* g2     = (float*)(g1 + (long long)8 * N);// 2N

    hipMemsetAsync(bhist, 0, (size_t)MAXB * sizeof(int), stream);

    k_bhist<<<HB_BLOCKS, 256, 0, stream>>>(dst, bhist, E, nbuck);
    k_bscan<<<1, 256, 0, stream>>>(bhist, bofs, cursor, rowptr, nbuck, N);
    k_binscatter<<<(E + CHUNK - 1) / CHUNK, 256, 0, stream>>>(src, dst, cursor, sedge, E, nbuck);
    k_sortnode<<<nbuck, 256, 0, stream>>>(bofs, sedge, csr, rowptr, dinv, N);

    k_gemm1<<<(N * 4 + 255) / 256, 256, 0, stream>>>(x, W1, dinv, g1, N);

    k_agg1<<<(N * 8 + 255) / 256, 256, 0, stream>>>(rowptr, csr, g1, dinv, b1, W2, g2, N);
    k_agg2<<<(N * 4 + 255) / 256, 256, 0, stream>>>(rowptr, csr, g2, dinv, b2, out, N);
}

// Round 11
// 158.006 us; speedup vs baseline: 1.3471x; 1.0033x over previous
//
#include <hip/hip_runtime.h>
#include <math.h>

#define F_IN 165
#define HID 16
#define NPB 256         // nodes per bucket
#define NPB_BITS 8
#define MAXB 512        // padded bucket-array size (nbuck=391)
#define CHUNK 4096      // edges per binscatter block
#define EPT 16          // CHUNK/256
#define SSTAGE 12288    // sortnode LDS staging capacity (avg bucket ~8192)
#define HB_BLOCKS 256   // k_bhist grid

__device__ __forceinline__ unsigned pk_bf16(float lo, float hi) {
    unsigned a = __float_as_uint(lo), b = __float_as_uint(hi);
    a += 0x7FFF + ((a >> 16) & 1);       // RNE
    b += 0x7FFF + ((b >> 16) & 1);
    return (a >> 16) | (b & 0xFFFF0000u);
}
#define BF_LO(w) __uint_as_float((w) << 16)
#define BF_HI(w) __uint_as_float((w) & 0xFFFF0000u)

// ---- bucket histogram: LDS-staged, ~100k global atomics total ----
__global__ __launch_bounds__(256) void k_bhist(const int* __restrict__ dst,
                                               int* __restrict__ bhist,
                                               int E, int nbuck) {
    __shared__ int h[MAXB];
    int t = threadIdx.x;
    for (int i = t; i < MAXB; i += 256) h[i] = 0;
    __syncthreads();
    int per = (E + gridDim.x - 1) / gridDim.x;
    int s0 = blockIdx.x * per;
    int s1 = min(E, s0 + per);
    for (int k = s0 + t; k < s1; k += 256)
        atomicAdd(&h[dst[k] >> NPB_BITS], 1);
    __syncthreads();
    for (int i = t; i < nbuck; i += 256) {
        int v = h[i];
        if (v) atomicAdd(&bhist[i], v);
    }
}

// ---- single-block exclusive scan of bucket counts -> bofs, cursor ----
__global__ __launch_bounds__(256) void k_bscan(const int* __restrict__ bhist,
                                               int* __restrict__ bofs,
                                               int* __restrict__ cursor,
                                               int* __restrict__ rowptr,
                                               int nbuck, int N) {
    __shared__ int ps[256];
    int t = threadIdx.x;
    int i0 = 2 * t, i1 = 2 * t + 1;
    int c0 = (i0 < nbuck) ? bhist[i0] : 0;
    int c1 = (i1 < nbuck) ? bhist[i1] : 0;
    int s = c0 + c1;
    ps[t] = s;
    __syncthreads();
    for (int off = 1; off < 256; off <<= 1) {
        int a = (t >= off) ? ps[t - off] : 0;
        __syncthreads();
        ps[t] += a;
        __syncthreads();
    }
    int excl = ps[t] - s;
    if (i0 < nbuck) { bofs[i0] = excl;      cursor[i0] = excl; }
    if (i1 < nbuck) { bofs[i1] = excl + c0; cursor[i1] = excl + c0; }
    if (t == 255) { bofs[nbuck] = ps[255]; rowptr[N] = ps[255]; }
}

// ---- counting-sort edges into bucket-major order, packed (src<<8)|dstlow ----
// Single LDS-atomic pass: the histogram atomicAdd's return IS the rank.
__global__ __launch_bounds__(256) void k_binscatter(const int* __restrict__ src,
                                                    const int* __restrict__ dst,
                                                    int* __restrict__ cursor,
                                                    unsigned* __restrict__ sedge,
                                                    int E, int nbuck) {
    __shared__ int hist[MAXB];
    __shared__ int lofs[MAXB];
    __shared__ int dlt[MAXB];       // gbase[b] - lofs[b]
    __shared__ int ps[256];
    __shared__ uint2 stg[CHUNK];
    int t = threadIdx.x;
    int e0 = blockIdx.x * CHUNK;
    int n = min(CHUNK, E - e0);

    int d[EPT], sv[EPT], rk[EPT];
#pragma unroll
    for (int u = 0; u < EPT; ++u) {
        int k = t + u * 256;
        d[u]  = (k < n) ? dst[e0 + k] : -1;
        sv[u] = (k < n) ? src[e0 + k] : 0;
    }
    for (int i = t; i < MAXB; i += 256) hist[i] = 0;
    __syncthreads();
#pragma unroll
    for (int u = 0; u < EPT; ++u)
        if (d[u] >= 0) rk[u] = atomicAdd(&hist[d[u] >> NPB_BITS], 1);
    __syncthreads();

    // block exclusive scan of hist (512 entries, 2 per thread)
    int base = t * 2;
    int h0 = hist[base], h1 = hist[base + 1];
    int s = h0 + h1;
    ps[t] = s;
    __syncthreads();
    for (int off = 1; off < 256; off <<= 1) {
        int a = (t >= off) ? ps[t - off] : 0;
        __syncthreads();
        ps[t] += a;
        __syncthreads();
    }
    int excl = ps[t] - s;
    lofs[base] = excl;
    lofs[base + 1] = excl + h0;
    __syncthreads();
    // reserve global space per non-empty bucket; dlt = gbase - lofs
    for (int i = t; i < nbuck; i += 256) {
        int h = hist[i];
        dlt[i] = (h ? atomicAdd(&cursor[i], h) : 0) - lofs[i];
    }
    __syncthreads();

    // place into bucket-major staging at r = lofs[b] + rank; addr fused in .y
#pragma unroll
    for (int u = 0; u < EPT; ++u) {
        if (d[u] < 0) continue;
        int b = d[u] >> NPB_BITS;
        int r = lofs[b] + rk[u];
        stg[r] = make_uint2(((unsigned)sv[u] << NPB_BITS) | (unsigned)(d[u] & (NPB - 1)),
                            (unsigned)(dlt[b] + r));
    }
    __syncthreads();

    // write-out: stride-1 LDS read pair + store (depth-1 chain)
    for (int r = t; r < n; r += 256) {
        uint2 v = stg[r];
        sedge[v.y] = v.x;
    }
}

// ---- within-bucket: node histogram (LDS) -> rowptr + dinv + sorted csr ----
__global__ __launch_bounds__(256) void k_sortnode(const int* __restrict__ bofs,
                                                  const unsigned* __restrict__ sedge,
                                                  int* __restrict__ csr,
                                                  int* __restrict__ rowptr,
                                                  float* __restrict__ dinv, int N) {
    __shared__ int hist[256];
    __shared__ int ps[256];
    __shared__ int lcur[256];
    __shared__ int stage[SSTAGE];
    int b = blockIdx.x, t = threadIdx.x;
    int base = bofs[b];
    int n = bofs[b + 1] - base;
    hist[t] = 0;
    __syncthreads();
    for (int k = t; k < n; k += 256)
        atomicAdd(&hist[sedge[base + k] & (NPB - 1)], 1);
    __syncthreads();
    int c = hist[t];
    ps[t] = c;
    __syncthreads();
    for (int off = 1; off < 256; off <<= 1) {
        int a = (t >= off) ? ps[t - off] : 0;
        __syncthreads();
        ps[t] += a;
        __syncthreads();
    }
    int excl = ps[t] - c;
    int node = b * NPB + t;
    if (node < N) {
        rowptr[node] = base + excl;
        dinv[node] = rsqrtf((float)c + 1.0f);
    }
    lcur[t] = excl;
    __syncthreads();
    bool staged = (n <= SSTAGE);
    for (int k = t; k < n; k += 256) {
        unsigned p = sedge[base + k];
        int d = p & (NPB - 1);
        int pos = atomicAdd(&lcur[d], 1);
        int sv = (int)(p >> NPB_BITS);
        if (staged) stage[pos] = sv;
        else        csr[base + pos] = sv;
    }
    __syncthreads();
    if (staged) {
        for (int k = t; k < n; k += 256) csr[base + k] = stage[k];
    }
}

// ---- g1 = bf16((x @ W1) * dinv[row]) ----
// 4 threads per row (4 cols each over all k): 400k threads = 24 waves/CU.
#define FMA1(vv, kk)                                                   \
    {                                                                  \
        float4 w = *(const float4*)(ws + (kk) * HID + c4);             \
        acc.x = fmaf((vv), w.x, acc.x); acc.y = fmaf((vv), w.y, acc.y);\
        acc.z = fmaf((vv), w.z, acc.z); acc.w = fmaf((vv), w.w, acc.w);\
    }

__global__ __launch_bounds__(256) void k_gemm1(const float* __restrict__ x,
                                               const float* __restrict__ W1,
                                               const float* __restrict__ dinv,
                                               unsigned* __restrict__ g1, int N) {
    __shared__ float ws[F_IN * HID];   // 10.5 KB
    int t = threadIdx.x;
    {
        const float4* w4 = (const float4*)W1;
        float4* s4 = (float4*)ws;
#pragma unroll
        for (int u = 0; u < 3; ++u) {
            int i = t + u * 256;
            if (i < (F_IN * HID) / 4) s4[i] = w4[i];
        }
    }
    __syncthreads();
    int gid = blockIdx.x * 256 + t;
    int row = gid >> 2;
    int c4 = (gid & 3) << 2;
    if (row >= N) return;
    const float* xr = x + (long long)row * F_IN;
    float4 acc = make_float4(0.f, 0.f, 0.f, 0.f);

    int p = (4 - (row & 3)) & 3;   // dwords to 16B boundary
    for (int k = 0; k < p; ++k) { float v = xr[k]; FMA1(v, k); }

    const float4* xr4 = (const float4*)(xr + p);
    int n4 = (F_IN - p) >> 2;      // 40 or 41
    int q = 0;
    for (; q + 4 <= n4; q += 4) {
        float4 v0 = xr4[q], v1 = xr4[q + 1], v2 = xr4[q + 2], v3 = xr4[q + 3];
        int kb = p + q * 4;
        FMA1(v0.x, kb + 0)  FMA1(v0.y, kb + 1)  FMA1(v0.z, kb + 2)  FMA1(v0.w, kb + 3)
        FMA1(v1.x, kb + 4)  FMA1(v1.y, kb + 5)  FMA1(v1.z, kb + 6)  FMA1(v1.w, kb + 7)
        FMA1(v2.x, kb + 8)  FMA1(v2.y, kb + 9)  FMA1(v2.z, kb + 10) FMA1(v2.w, kb + 11)
        FMA1(v3.x, kb + 12) FMA1(v3.y, kb + 13) FMA1(v3.z, kb + 14) FMA1(v3.w, kb + 15)
    }
    for (; q < n4; ++q) {
        float4 v = xr4[q];
        int kb = p + q * 4;
        FMA1(v.x, kb) FMA1(v.y, kb + 1) FMA1(v.z, kb + 2) FMA1(v.w, kb + 3)
    }
    for (int k = p + n4 * 4; k < F_IN; ++k) { float v = xr[k]; FMA1(v, k); }

    float di = dinv[row];
    uint2 o = make_uint2(pk_bf16(acc.x * di, acc.y * di),
                         pk_bf16(acc.z * di, acc.w * di));
    *(uint2*)(g1 + (long long)row * 8 + (gid & 3) * 2) = o;
}

// ---- layer-1 CSR gather (bf16 rows), fp32 accum, fused bias/relu/W2 -> g2 ----
__global__ __launch_bounds__(256) void k_agg1(const int* __restrict__ rowptr,
                                              const int* __restrict__ csr,
                                              const unsigned* __restrict__ g1,
                                              const float* __restrict__ dinv,
                                              const float* __restrict__ b1,
                                              const float* __restrict__ W2,
                                              float* __restrict__ g2, int N) {
    int gid = blockIdx.x * 256 + threadIdx.x;
    int i = gid >> 3;
    int j = gid & 7;
    if (i >= N) return;
    int e0 = rowptr[i], e1 = rowptr[i + 1];
    unsigned w0 = g1[i * 8 + j];           // self-loop term
    float a0 = BF_LO(w0), a1 = BF_HI(w0);
    int e = e0;
    for (; e + 8 <= e1; e += 8) {
        int s0 = csr[e],     s1 = csr[e + 1], s2 = csr[e + 2], s3 = csr[e + 3];
        int s4 = csr[e + 4], s5 = csr[e + 5], s6 = csr[e + 6], s7 = csr[e + 7];
        unsigned u0 = g1[s0 * 8 + j], u1 = g1[s1 * 8 + j];
        unsigned u2 = g1[s2 * 8 + j], u3 = g1[s3 * 8 + j];
        unsigned u4 = g1[s4 * 8 + j], u5 = g1[s5 * 8 + j];
        unsigned u6 = g1[s6 * 8 + j], u7 = g1[s7 * 8 + j];
        a0 += ((BF_LO(u0) + BF_LO(u1)) + (BF_LO(u2) + BF_LO(u3))) +
              ((BF_LO(u4) + BF_LO(u5)) + (BF_LO(u6) + BF_LO(u7)));
        a1 += ((BF_HI(u0) + BF_HI(u1)) + (BF_HI(u2) + BF_HI(u3))) +
              ((BF_HI(u4) + BF_HI(u5)) + (BF_HI(u6) + BF_HI(u7)));
    }
    for (; e < e1; ++e) {
        unsigned u = g1[csr[e] * 8 + j];
        a0 += BF_LO(u);
        a1 += BF_HI(u);
    }
    float di = dinv[i];
    float v0 = fmaf(a0, di, b1[2 * j]);     v0 = v0 > 0.f ? v0 : 0.f;
    float v1 = fmaf(a1, di, b1[2 * j + 1]); v1 = v1 > 0.f ? v1 : 0.f;
    float4 w = ((const float4*)W2)[j];      // W2[2j][0..1], W2[2j+1][0..1]
    float c0 = fmaf(v1, w.z, v0 * w.x);
    float c1 = fmaf(v1, w.w, v0 * w.y);
    for (int off = 4; off; off >>= 1) {
        c0 += __shfl_xor(c0, off, 8);
        c1 += __shfl_xor(c1, off, 8);
    }
    if (j == 0) ((float2*)g2)[i] = make_float2(c0 * di, c1 * di);
}

// ---- layer-2 CSR gather + fused log_softmax -> out (4 lanes/node) ----
__global__ __launch_bounds__(256) void k_agg2(const int* __restrict__ rowptr,
                                              const int* __restrict__ csr,
                                              const float* __restrict__ g2,
                                              const float* __restrict__ dinv,
                                              const float* __restrict__ b2,
                                              float* __restrict__ out, int N) {
    int gid = blockIdx.x * 256 + threadIdx.x;
    int i = gid >> 2;
    int l = gid & 3;
    if (i >= N) return;
    int e0 = rowptr[i], e1 = rowptr[i + 1];
    float a0 = 0.f, a1 = 0.f;
    int e = e0 + l;
    for (; e + 4 < e1; e += 8) {
        int s0 = csr[e], s1 = csr[e + 4];
        float2 u = ((const float2*)g2)[s0];
        float2 w = ((const float2*)g2)[s1];
        a0 += u.x + w.x;
        a1 += u.y + w.y;
    }
    for (; e < e1; e += 4) {
        int s = csr[e];
        float2 u = ((const float2*)g2)[s];
        a0 += u.x;
        a1 += u.y;
    }
    a0 += __shfl_xor(a0, 1, 4); a0 += __shfl_xor(a0, 2, 4);
    a1 += __shfl_xor(a1, 1, 4); a1 += __shfl_xor(a1, 2, 4);
    if (l == 0) {
        float2 self = ((const float2*)g2)[i];
        float di = dinv[i];
        float A = fmaf(a0 + self.x, di, b2[0]);
        float B = fmaf(a1 + self.y, di, b2[1]);
        float m = fmaxf(A, B);
        float lse = m + logf(expf(A - m) + expf(B - m));
        ((float2*)out)[i] = make_float2(A - lse, B - lse);
    }
}

extern "C" void kernel_launch(void* const* d_in, const int* in_sizes, int n_in,
                              void* d_out, int out_size, void* d_ws, size_t ws_size,
                              hipStream_t stream) {
    const float* x  = (const float*)d_in[0];
    const int*   ei = (const int*)d_in[1];
    const float* W1 = (const float*)d_in[2];
    const float* b1 = (const float*)d_in[3];
    const float* W2 = (const float*)d_in[4];
    const float* b2 = (const float*)d_in[5];
    float* out = (float*)d_out;

    int N = in_sizes[0] / F_IN;
    int E = in_sizes[1] / 2;
    const int* src = ei;
    const int* dst = ei + E;
    int nbuck = (N + NPB - 1) >> NPB_BITS;

    int* bhist    = (int*)d_ws;                     // MAXB
    int* bofs     = bhist + MAXB;                   // MAXB+1
    int* cursor   = bofs + MAXB + 1;                // MAXB
    int* rowptr   = cursor + MAXB;                  // N+1
    unsigned* sedge = (unsigned*)(rowptr + N + 1);  // E
    int* csr      = (int*)(sedge + E);              // E
    float* dinv   = (float*)(csr + E);              // N
    unsigned* g1  = (unsigned*)(dinv + N);          // 8N (bf16 rows)
    float* g2     = (float*)(g1 + (long long)8 * N);// 2N

    hipMemsetAsync(bhist, 0, (size_t)MAXB * sizeof(int), stream);

    k_bhist<<<HB_BLOCKS, 256, 0, stream>>>(dst, bhist, E, nbuck);
    k_bscan<<<1, 256, 0, stream>>>(bhist, bofs, cursor, rowptr, nbuck, N);
    k_binscatter<<<(E + CHUNK - 1) / CHUNK, 256, 0, stream>>>(src, dst, cursor, sedge, E, nbuck);
    k_sortnode<<<nbuck, 256, 0, stream>>>(bofs, sedge, csr, rowptr, dinv, N);

    k_gemm1<<<(N * 4 + 255) / 256, 256, 0, stream>>>(x, W1, dinv, g1, N);

    k_agg1<<<(N * 8 + 255) / 256, 256, 0, stream>>>(rowptr, csr, g1, dinv, b1, W2, g2, N);
    k_agg2<<<(N * 4 + 255) / 256, 256, 0, stream>>>(rowptr, csr, g2, dinv, b2, out, N);
}

// Round 12
// 128.138 us; speedup vs baseline: 1.6611x; 1.2331x over previous
//
#include <hip/hip_runtime.h>
#include <math.h>

#define F_IN 165
#define HID 16
#define NPB 256         // nodes per bucket
#define NPB_BITS 8
#define MAXB 512        // padded bucket-array size (nbuck=391)
#define CHUNK 4096      // edges per chunk (k_cnt / k_binscatter block)
#define EPT 16          // CHUNK/256
#define SSTAGE 12288    // sortnode LDS staging capacity (avg bucket ~8192)

__device__ __forceinline__ unsigned pk_bf16(float lo, float hi) {
    unsigned a = __float_as_uint(lo), b = __float_as_uint(hi);
    a += 0x7FFF + ((a >> 16) & 1);       // RNE
    b += 0x7FFF + ((b >> 16) & 1);
    return (a >> 16) | (b & 0xFFFF0000u);
}
#define BF_LO(w) __uint_as_float((w) << 16)
#define BF_HI(w) __uint_as_float((w) & 0xFFFF0000u)

// ---- per-chunk bucket histogram -> cbM[chunk][MAXB] (coalesced row) ----
__global__ __launch_bounds__(256) void k_cnt(const int* __restrict__ dst,
                                             int* __restrict__ cbM, int E) {
    __shared__ int h[MAXB];
    int t = threadIdx.x;
    for (int i = t; i < MAXB; i += 256) h[i] = 0;
    __syncthreads();
    int e0 = blockIdx.x * CHUNK;
    int n = min(CHUNK, E - e0);
    for (int k = t; k < n; k += 256)
        atomicAdd(&h[dst[e0 + k] >> NPB_BITS], 1);
    __syncthreads();
    for (int i = t; i < MAXB; i += 256)
        cbM[blockIdx.x * MAXB + i] = h[i];
}

// ---- per-bucket column scan (in place): cbM[c][b] -> excl prefix; btot[b] ----
__global__ __launch_bounds__(256) void k_colscan(int* __restrict__ cbM,
                                                 int* __restrict__ btot, int NB) {
    __shared__ int ps[256];
    int b = blockIdx.x, t = threadIdx.x;
    int i0 = t * 4;
    int v[4];
    int s = 0;
#pragma unroll
    for (int u = 0; u < 4; ++u) {
        int c = i0 + u;
        v[u] = (c < NB) ? cbM[c * MAXB + b] : 0;
        s += v[u];
    }
    ps[t] = s;
    __syncthreads();
    for (int off = 1; off < 256; off <<= 1) {
        int a = (t >= off) ? ps[t - off] : 0;
        __syncthreads();
        ps[t] += a;
        __syncthreads();
    }
    int run = ps[t] - s;
#pragma unroll
    for (int u = 0; u < 4; ++u) {
        int c = i0 + u;
        if (c < NB) cbM[c * MAXB + b] = run;
        run += v[u];
    }
    if (t == 255) btot[b] = ps[255];
}

// ---- single-block exclusive scan of bucket totals -> bofs ----
__global__ __launch_bounds__(256) void k_bscan(const int* __restrict__ btot,
                                               int* __restrict__ bofs,
                                               int* __restrict__ rowptr,
                                               int nbuck, int N) {
    __shared__ int ps[256];
    int t = threadIdx.x;
    int i0 = 2 * t, i1 = 2 * t + 1;
    int c0 = (i0 < nbuck) ? btot[i0] : 0;
    int c1 = (i1 < nbuck) ? btot[i1] : 0;
    int s = c0 + c1;
    ps[t] = s;
    __syncthreads();
    for (int off = 1; off < 256; off <<= 1) {
        int a = (t >= off) ? ps[t - off] : 0;
        __syncthreads();
        ps[t] += a;
        __syncthreads();
    }
    int excl = ps[t] - s;
    if (i0 < nbuck) bofs[i0] = excl;
    if (i1 < nbuck) bofs[i1] = excl + c0;
    if (t == 255) { bofs[nbuck] = ps[255]; rowptr[N] = ps[255]; }
}

// ---- counting-sort edges into bucket-major order, packed (src<<8)|dstlow ----
// ZERO global atomics: write base = bofs[b] + cbM[me][b] (deterministic).
__global__ __launch_bounds__(256) void k_binscatter(const int* __restrict__ src,
                                                    const int* __restrict__ dst,
                                                    const int* __restrict__ cbM,
                                                    const int* __restrict__ bofs,
                                                    unsigned* __restrict__ sedge,
                                                    int E, int nbuck) {
    __shared__ int hist[MAXB];
    __shared__ int lofs[MAXB];
    __shared__ int dlt[MAXB];       // (bofs[b] + cbM[me][b]) - lofs[b]
    __shared__ int ps[256];
    __shared__ uint2 stg[CHUNK];
    int t = threadIdx.x;
    int me = blockIdx.x;
    int e0 = me * CHUNK;
    int n = min(CHUNK, E - e0);

    int d[EPT], sv[EPT], rk[EPT];
#pragma unroll
    for (int u = 0; u < EPT; ++u) {
        int k = t + u * 256;
        d[u]  = (k < n) ? dst[e0 + k] : -1;
        sv[u] = (k < n) ? src[e0 + k] : 0;
    }
    for (int i = t; i < MAXB; i += 256) hist[i] = 0;
    __syncthreads();
#pragma unroll
    for (int u = 0; u < EPT; ++u)
        if (d[u] >= 0) rk[u] = atomicAdd(&hist[d[u] >> NPB_BITS], 1);
    __syncthreads();

    // block exclusive scan of hist (512 entries, 2 per thread)
    int base = t * 2;
    int h0 = hist[base], h1 = hist[base + 1];
    int s = h0 + h1;
    ps[t] = s;
    __syncthreads();
    for (int off = 1; off < 256; off <<= 1) {
        int a = (t >= off) ? ps[t - off] : 0;
        __syncthreads();
        ps[t] += a;
        __syncthreads();
    }
    int excl = ps[t] - s;
    lofs[base] = excl;
    lofs[base + 1] = excl + h0;
    __syncthreads();
    for (int i = t; i < nbuck; i += 256)
        dlt[i] = bofs[i] + cbM[me * MAXB + i] - lofs[i];
    __syncthreads();

    // place into bucket-major staging at r = lofs[b] + rank; addr fused in .y
#pragma unroll
    for (int u = 0; u < EPT; ++u) {
        if (d[u] < 0) continue;
        int b = d[u] >> NPB_BITS;
        int r = lofs[b] + rk[u];
        stg[r] = make_uint2(((unsigned)sv[u] << NPB_BITS) | (unsigned)(d[u] & (NPB - 1)),
                            (unsigned)(dlt[b] + r));
    }
    __syncthreads();

    // write-out: stride-1 LDS read pair + store (depth-1 chain)
    for (int r = t; r < n; r += 256) {
        uint2 v = stg[r];
        sedge[v.y] = v.x;
    }
}

// ---- within-bucket: node histogram (LDS) -> rowptr + dinv + sorted csr ----
__global__ __launch_bounds__(256) void k_sortnode(const int* __restrict__ bofs,
                                                  const unsigned* __restrict__ sedge,
                                                  int* __restrict__ csr,
                                                  int* __restrict__ rowptr,
                                                  float* __restrict__ dinv, int N) {
    __shared__ int hist[256];
    __shared__ int ps[256];
    __shared__ int lcur[256];
    __shared__ int stage[SSTAGE];
    int b = blockIdx.x, t = threadIdx.x;
    int base = bofs[b];
    int n = bofs[b + 1] - base;
    hist[t] = 0;
    __syncthreads();
    for (int k = t; k < n; k += 256)
        atomicAdd(&hist[sedge[base + k] & (NPB - 1)], 1);
    __syncthreads();
    int c = hist[t];
    ps[t] = c;
    __syncthreads();
    for (int off = 1; off < 256; off <<= 1) {
        int a = (t >= off) ? ps[t - off] : 0;
        __syncthreads();
        ps[t] += a;
        __syncthreads();
    }
    int excl = ps[t] - c;
    int node = b * NPB + t;
    if (node < N) {
        rowptr[node] = base + excl;
        dinv[node] = rsqrtf((float)c + 1.0f);
    }
    lcur[t] = excl;
    __syncthreads();
    bool staged = (n <= SSTAGE);
    for (int k = t; k < n; k += 256) {
        unsigned p = sedge[base + k];
        int d = p & (NPB - 1);
        int pos = atomicAdd(&lcur[d], 1);
        int sv = (int)(p >> NPB_BITS);
        if (staged) stage[pos] = sv;
        else        csr[base + pos] = sv;
    }
    __syncthreads();
    if (staged) {
        for (int k = t; k < n; k += 256) csr[base + k] = stage[k];
    }
}

// ---- g1 = bf16((x @ W1) * dinv[row]) ----
// 4 threads per row (4 cols each over all k): 400k threads = 24 waves/CU.
#define FMA1(vv, kk)                                                   \
    {                                                                  \
        float4 w = *(const float4*)(ws + (kk) * HID + c4);             \
        acc.x = fmaf((vv), w.x, acc.x); acc.y = fmaf((vv), w.y, acc.y);\
        acc.z = fmaf((vv), w.z, acc.z); acc.w = fmaf((vv), w.w, acc.w);\
    }

__global__ __launch_bounds__(256) void k_gemm1(const float* __restrict__ x,
                                               const float* __restrict__ W1,
                                               const float* __restrict__ dinv,
                                               unsigned* __restrict__ g1, int N) {
    __shared__ float ws[F_IN * HID];   // 10.5 KB
    int t = threadIdx.x;
    {
        const float4* w4 = (const float4*)W1;
        float4* s4 = (float4*)ws;
#pragma unroll
        for (int u = 0; u < 3; ++u) {
            int i = t + u * 256;
            if (i < (F_IN * HID) / 4) s4[i] = w4[i];
        }
    }
    __syncthreads();
    int gid = blockIdx.x * 256 + t;
    int row = gid >> 2;
    int c4 = (gid & 3) << 2;
    if (row >= N) return;
    const float* xr = x + (long long)row * F_IN;
    float4 acc = make_float4(0.f, 0.f, 0.f, 0.f);

    int p = (4 - (row & 3)) & 3;   // dwords to 16B boundary
    for (int k = 0; k < p; ++k) { float v = xr[k]; FMA1(v, k); }

    const float4* xr4 = (const float4*)(xr + p);
    int n4 = (F_IN - p) >> 2;      // 40 or 41
    int q = 0;
    for (; q + 4 <= n4; q += 4) {
        float4 v0 = xr4[q], v1 = xr4[q + 1], v2 = xr4[q + 2], v3 = xr4[q + 3];
        int kb = p + q * 4;
        FMA1(v0.x, kb + 0)  FMA1(v0.y, kb + 1)  FMA1(v0.z, kb + 2)  FMA1(v0.w, kb + 3)
        FMA1(v1.x, kb + 4)  FMA1(v1.y, kb + 5)  FMA1(v1.z, kb + 6)  FMA1(v1.w, kb + 7)
        FMA1(v2.x, kb + 8)  FMA1(v2.y, kb + 9)  FMA1(v2.z, kb + 10) FMA1(v2.w, kb + 11)
        FMA1(v3.x, kb + 12) FMA1(v3.y, kb + 13) FMA1(v3.z, kb + 14) FMA1(v3.w, kb + 15)
    }
    for (; q < n4; ++q) {
        float4 v = xr4[q];
        int kb = p + q * 4;
        FMA1(v.x, kb) FMA1(v.y, kb + 1) FMA1(v.z, kb + 2) FMA1(v.w, kb + 3)
    }
    for (int k = p + n4 * 4; k < F_IN; ++k) { float v = xr[k]; FMA1(v, k); }

    float di = dinv[row];
    uint2 o = make_uint2(pk_bf16(acc.x * di, acc.y * di),
                         pk_bf16(acc.z * di, acc.w * di));
    *(uint2*)(g1 + (long long)row * 8 + (gid & 3) * 2) = o;
}

// ---- layer-1 CSR gather (bf16 rows), fp32 accum, fused bias/relu/W2 -> g2 ----
__global__ __launch_bounds__(256) void k_agg1(const int* __restrict__ rowptr,
                                              const int* __restrict__ csr,
                                              const unsigned* __restrict__ g1,
                                              const float* __restrict__ dinv,
                                              const float* __restrict__ b1,
                                              const float* __restrict__ W2,
                                              float* __restrict__ g2, int N) {
    int gid = blockIdx.x * 256 + threadIdx.x;
    int i = gid >> 3;
    int j = gid & 7;
    if (i >= N) return;
    int e0 = rowptr[i], e1 = rowptr[i + 1];
    unsigned w0 = g1[i * 8 + j];           // self-loop term
    float a0 = BF_LO(w0), a1 = BF_HI(w0);
    int e = e0;
    for (; e + 8 <= e1; e += 8) {
        int s0 = csr[e],     s1 = csr[e + 1], s2 = csr[e + 2], s3 = csr[e + 3];
        int s4 = csr[e + 4], s5 = csr[e + 5], s6 = csr[e + 6], s7 = csr[e + 7];
        unsigned u0 = g1[s0 * 8 + j], u1 = g1[s1 * 8 + j];
        unsigned u2 = g1[s2 * 8 + j], u3 = g1[s3 * 8 + j];
        unsigned u4 = g1[s4 * 8 + j], u5 = g1[s5 * 8 + j];
        unsigned u6 = g1[s6 * 8 + j], u7 = g1[s7 * 8 + j];
        a0 += ((BF_LO(u0) + BF_LO(u1)) + (BF_LO(u2) + BF_LO(u3))) +
              ((BF_LO(u4) + BF_LO(u5)) + (BF_LO(u6) + BF_LO(u7)));
        a1 += ((BF_HI(u0) + BF_HI(u1)) + (BF_HI(u2) + BF_HI(u3))) +
              ((BF_HI(u4) + BF_HI(u5)) + (BF_HI(u6) + BF_HI(u7)));
    }
    for (; e < e1; ++e) {
        unsigned u = g1[csr[e] * 8 + j];
        a0 += BF_LO(u);
        a1 += BF_HI(u);
    }
    float di = dinv[i];
    float v0 = fmaf(a0, di, b1[2 * j]);     v0 = v0 > 0.f ? v0 : 0.f;
    float v1 = fmaf(a1, di, b1[2 * j + 1]); v1 = v1 > 0.f ? v1 : 0.f;
    float4 w = ((const float4*)W2)[j];      // W2[2j][0..1], W2[2j+1][0..1]
    float c0 = fmaf(v1, w.z, v0 * w.x);
    float c1 = fmaf(v1, w.w, v0 * w.y);
    for (int off = 4; off; off >>= 1) {
        c0 += __shfl_xor(c0, off, 8);
        c1 += __shfl_xor(c1, off, 8);
    }
    if (j == 0) ((float2*)g2)[i] = make_float2(c0 * di, c1 * di);
}

// ---- layer-2 CSR gather + fused log_softmax -> out (4 lanes/node) ----
__global__ __launch_bounds__(256) void k_agg2(const int* __restrict__ rowptr,
                                              const int* __restrict__ csr,
                                              const float* __restrict__ g2,
                                              const float* __restrict__ dinv,
                                              const float* __restrict__ b2,
                                              float* __restrict__ out, int N) {
    int gid = blockIdx.x * 256 + threadIdx.x;
    int i = gid >> 2;
    int l = gid & 3;
    if (i >= N) return;
    int e0 = rowptr[i], e1 = rowptr[i + 1];
    float a0 = 0.f, a1 = 0.f;
    int e = e0 + l;
    for (; e + 4 < e1; e += 8) {
        int s0 = csr[e], s1 = csr[e + 4];
        float2 u = ((const float2*)g2)[s0];
        float2 w = ((const float2*)g2)[s1];
        a0 += u.x + w.x;
        a1 += u.y + w.y;
    }
    for (; e < e1; e += 4) {
        int s = csr[e];
        float2 u = ((const float2*)g2)[s];
        a0 += u.x;
        a1 += u.y;
    }
    a0 += __shfl_xor(a0, 1, 4); a0 += __shfl_xor(a0, 2, 4);
    a1 += __shfl_xor(a1, 1, 4); a1 += __shfl_xor(a1, 2, 4);
    if (l == 0) {
        float2 self = ((const float2*)g2)[i];
        float di = dinv[i];
        float A = fmaf(a0 + self.x, di, b2[0]);
        float B = fmaf(a1 + self.y, di, b2[1]);
        float m = fmaxf(A, B);
        float lse = m + logf(expf(A - m) + expf(B - m));
        ((float2*)out)[i] = make_float2(A - lse, B - lse);
    }
}

extern "C" void kernel_launch(void* const* d_in, const int* in_sizes, int n_in,
                              void* d_out, int out_size, void* d_ws, size_t ws_size,
                              hipStream_t stream) {
    const float* x  = (const float*)d_in[0];
    const int*   ei = (const int*)d_in[1];
    const float* W1 = (const float*)d_in[2];
    const float* b1 = (const float*)d_in[3];
    const float* W2 = (const float*)d_in[4];
    const float* b2 = (const float*)d_in[5];
    float* out = (float*)d_out;

    int N = in_sizes[0] / F_IN;
    int E = in_sizes[1] / 2;
    const int* src = ei;
    const int* dst = ei + E;
    int nbuck = (N + NPB - 1) >> NPB_BITS;
    int NB = (E + CHUNK - 1) / CHUNK;

    int* cbM      = (int*)d_ws;                     // NB*MAXB (counts -> excl offsets)
    int* btot     = cbM + (long long)NB * MAXB;     // MAXB
    int* bofs     = btot + MAXB;                    // MAXB+1
    int* rowptr   = bofs + MAXB + 1;                // N+1
    unsigned* sedge = (unsigned*)(rowptr + N + 1);  // E
    int* csr      = (int*)(sedge + E);              // E
    float* dinv   = (float*)(csr + E);              // N
    unsigned* g1  = (unsigned*)(dinv + N);          // 8N (bf16 rows)
    float* g2     = (float*)(g1 + (long long)8 * N);// 2N

    k_cnt<<<NB, 256, 0, stream>>>(dst, cbM, E);
    k_colscan<<<nbuck, 256, 0, stream>>>(cbM, btot, NB);
    k_bscan<<<1, 256, 0, stream>>>(btot, bofs, rowptr, nbuck, N);
    k_binscatter<<<NB, 256, 0, stream>>>(src, dst, cbM, bofs, sedge, E, nbuck);
    k_sortnode<<<nbuck, 256, 0, stream>>>(bofs, sedge, csr, rowptr, dinv, N);

    k_gemm1<<<(N * 4 + 255) / 256, 256, 0, stream>>>(x, W1, dinv, g1, N);

    k_agg1<<<(N * 8 + 255) / 256, 256, 0, stream>>>(rowptr, csr, g1, dinv, b1, W2, g2, N);
    k_agg2<<<(N * 4 + 255) / 256, 256, 0, stream>>>(rowptr, csr, g2, dinv, b2, out, N);
}